// Round 1
// baseline (1477.092 us; speedup 1.0000x reference)
//
#include <hip/hip_runtime.h>
#include <math.h>

#define HDIM 512
#define BATCH 128

__device__ __forceinline__ float fast_tanh(float x) {
  // tanh(x) = 1 - 2/(e^{2x}+1); saturates correctly for |x| large.
  float e = __expf(2.0f * x);
  return 1.0f - 2.0f / (e + 1.0f);
}

// ---------------------------------------------------------------------------
// Fused logit GEMM: logits[m] += sum_n v[n] * tanh( (A@W)[m,n] + bias[n] )
// A: M x 512 (optionally tanh'd on load), W: 512 x 512.
// Block tile 128(M) x 64(N), BK=16, 256 threads, 8x4 micro-tile.
// grid = (512/64 = 8 n-blocks [x, fastest -> A-tile L2 reuse], M/128 m-blocks)
// logits must be zero-initialized (the +c constant is softmax-invariant, skipped).
// ---------------------------------------------------------------------------
template <bool TANH_IN>
__global__ __launch_bounds__(256) void gemm_logits_kernel(
    const float* __restrict__ A, const float* __restrict__ W,
    const float* __restrict__ bias, const float* __restrict__ vvec,
    float* __restrict__ logits) {
  constexpr int BM = 128, BN = 64, BK = 16;
  __shared__ __align__(16) float As[BK][BM];      // k-major: As[k][m]
  __shared__ __align__(16) float Bs[BK][BN + 4];  // +4 pad breaks store conflicts

  const int tid = threadIdx.x;
  const int tx = tid & 15, ty = tid >> 4;
  const int m0 = blockIdx.y * BM;
  const int n0 = blockIdx.x * BN;

  float acc[8][4];
#pragma unroll
  for (int i = 0; i < 8; ++i)
#pragma unroll
    for (int j = 0; j < 4; ++j) acc[i][j] = 0.0f;

  const int rA = tid >> 2;        // 0..63 (row within half of A tile)
  const int cA = (tid & 3) * 4;   // 0,4,8,12
  const int rB = tid >> 4;        // 0..15
  const int cB = (tid & 15) * 4;  // 0..60

  for (int k0 = 0; k0 < HDIM; k0 += BK) {
    // A tile: 128x16, fully coalesced 64B runs, stored transposed to As[k][m]
#pragma unroll
    for (int i = 0; i < 2; ++i) {
      const int r = rA + i * 64;
      float4 a = *(const float4*)(A + (size_t)(m0 + r) * HDIM + k0 + cA);
      if (TANH_IN) {
        a.x = fast_tanh(a.x); a.y = fast_tanh(a.y);
        a.z = fast_tanh(a.z); a.w = fast_tanh(a.w);
      }
      As[cA + 0][r] = a.x;
      As[cA + 1][r] = a.y;
      As[cA + 2][r] = a.z;
      As[cA + 3][r] = a.w;
    }
    // W tile: 16x64, coalesced, direct float4 store
    {
      float4 b4 = *(const float4*)(W + (size_t)(k0 + rB) * HDIM + n0 + cB);
      *(float4*)&Bs[rB][cB] = b4;
    }
    __syncthreads();
#pragma unroll
    for (int kk = 0; kk < BK; ++kk) {
      const float4 a0 = *(const float4*)&As[kk][ty * 8];
      const float4 a1 = *(const float4*)&As[kk][ty * 8 + 4];
      const float4 b4 = *(const float4*)&Bs[kk][tx * 4];
      const float av[8] = {a0.x, a0.y, a0.z, a0.w, a1.x, a1.y, a1.z, a1.w};
      const float bv[4] = {b4.x, b4.y, b4.z, b4.w};
#pragma unroll
      for (int i = 0; i < 8; ++i)
#pragma unroll
        for (int j = 0; j < 4; ++j) acc[i][j] = fmaf(av[i], bv[j], acc[i][j]);
    }
    __syncthreads();
  }

  // Epilogue: t = tanh(acc + bias[n]) * v[n]; reduce over the 64 n's of this block.
  float vn[4], bn[4];
#pragma unroll
  for (int j = 0; j < 4; ++j) {
    vn[j] = vvec[n0 + tx * 4 + j];
    bn[j] = bias[n0 + tx * 4 + j];
  }
#pragma unroll
  for (int i = 0; i < 8; ++i) {
    float s = 0.0f;
#pragma unroll
    for (int j = 0; j < 4; ++j) s = fmaf(vn[j], fast_tanh(acc[i][j] + bn[j]), s);
    // reduce across tx (low 4 lane bits)
    s += __shfl_xor(s, 1);
    s += __shfl_xor(s, 2);
    s += __shfl_xor(s, 4);
    s += __shfl_xor(s, 8);
    if (tx == 0) atomicAdd(&logits[m0 + ty * 8 + i], s);
  }
}

__global__ void zero_kernel(float* __restrict__ p, int n) {
  const int i = blockIdx.x * 256 + threadIdx.x;
  if (i < n) p[i] = 0.0f;
}

// seg_start[b] = lower_bound(seg_ids, b); seg_start[BATCH] = N
__global__ void seg_bounds_kernel(const int* __restrict__ seg, int N,
                                  int* __restrict__ seg_start) {
  const int b = threadIdx.x;
  if (b > BATCH) return;
  int lo = 0, hi = N;
  while (lo < hi) {
    const int mid = (lo + hi) >> 1;
    if (seg[mid] < b) lo = mid + 1; else hi = mid;
  }
  seg_start[b] = lo;
}

// In-place masked softmax over each row of logits[B][S]; masked entries -> 0.
__global__ __launch_bounds__(256) void softmax_masked_kernel(
    float* __restrict__ logits, const int* __restrict__ lens, int S) {
  __shared__ float smax[4], ssum[4];
  const int b = blockIdx.x, tid = threadIdx.x;
  const int len = lens[b];
  float* l = logits + (size_t)b * S;
  float mymax = -1e30f;
  for (int s = tid; s < len; s += 256) mymax = fmaxf(mymax, l[s]);
#pragma unroll
  for (int off = 32; off; off >>= 1) mymax = fmaxf(mymax, __shfl_xor(mymax, off));
  if ((tid & 63) == 0) smax[tid >> 6] = mymax;
  __syncthreads();
  const float bmax = fmaxf(fmaxf(smax[0], smax[1]), fmaxf(smax[2], smax[3]));
  float mysum = 0.0f;
  for (int s = tid; s < len; s += 256) mysum += __expf(l[s] - bmax);
#pragma unroll
  for (int off = 32; off; off >>= 1) mysum += __shfl_xor(mysum, off);
  if ((tid & 63) == 0) ssum[tid >> 6] = mysum;
  __syncthreads();
  const float inv = 1.0f / (ssum[0] + ssum[1] + ssum[2] + ssum[3]);
  for (int s = tid; s < S; s += 256)
    l[s] = (s < len) ? __expf(l[s] - bmax) * inv : 0.0f;
}

// In-place softmax over each segment range [seg_start[b], seg_start[b+1]).
__global__ __launch_bounds__(256) void softmax_seg_kernel(
    float* __restrict__ logits, const int* __restrict__ seg_start) {
  __shared__ float smax[4], ssum[4];
  const int b = blockIdx.x, tid = threadIdx.x;
  const int s0 = seg_start[b], s1 = seg_start[b + 1];
  float mymax = -1e30f;
  for (int s = s0 + tid; s < s1; s += 256) mymax = fmaxf(mymax, logits[s]);
#pragma unroll
  for (int off = 32; off; off >>= 1) mymax = fmaxf(mymax, __shfl_xor(mymax, off));
  if ((tid & 63) == 0) smax[tid >> 6] = mymax;
  __syncthreads();
  const float bmax = fmaxf(fmaxf(smax[0], smax[1]), fmaxf(smax[2], smax[3]));
  float mysum = 0.0f;
  for (int s = s0 + tid; s < s1; s += 256) mysum += __expf(logits[s] - bmax);
#pragma unroll
  for (int off = 32; off; off >>= 1) mysum += __shfl_xor(mysum, off);
  if ((tid & 63) == 0) ssum[tid >> 6] = mysum;
  __syncthreads();
  const float inv = 1.0f / (ssum[0] + ssum[1] + ssum[2] + ssum[3]);
  for (int s = s0 + tid; s < s1; s += 256)
    logits[s] = __expf(logits[s] - bmax) * inv;
}

// pool[b,h] += sum_{s in chunk} w[b,s] * feat[b,s,h]; grid (B, S/chunk)
__global__ __launch_bounds__(256) void pool_masked_kernel(
    const float* __restrict__ feat, const float* __restrict__ w,
    float* __restrict__ pool, int S, int chunk) {
  const int b = blockIdx.x, c = blockIdx.y, tid = threadIdx.x;
  const int h0 = tid * 2;
  const int s0 = c * chunk;
  const int s1 = min(S, s0 + chunk);
  const float* fb = feat + (size_t)b * S * HDIM;
  const float* wb = w + (size_t)b * S;
  float ax = 0.0f, ay = 0.0f;
  for (int s = s0; s < s1; ++s) {
    const float ws = wb[s];  // block-uniform -> uniform branch, skips masked rows
    if (ws != 0.0f) {
      const float2 f = *(const float2*)(fb + (size_t)s * HDIM + h0);
      ax = fmaf(ws, f.x, ax);
      ay = fmaf(ws, f.y, ay);
    }
  }
  atomicAdd(&pool[b * HDIM + h0], ax);
  atomicAdd(&pool[b * HDIM + h0 + 1], ay);
}

// ast_pool[b,h] += sum_{n in seg b chunk} w[n] * tanh(node_h[n,h]); grid (B, 4)
__global__ __launch_bounds__(256) void pool_seg_kernel(
    const float* __restrict__ node_h, const float* __restrict__ w,
    const int* __restrict__ seg_start, float* __restrict__ pool) {
  const int b = blockIdx.x, c = blockIdx.y, tid = threadIdx.x;
  const int h0 = tid * 2;
  const int s0 = seg_start[b], s1 = seg_start[b + 1];
  const int nseg = s1 - s0;
  const int chunk = (nseg + (int)gridDim.y - 1) / (int)gridDim.y;
  const int a0 = s0 + c * chunk;
  const int a1 = min(s1, a0 + chunk);
  float ax = 0.0f, ay = 0.0f;
  for (int s = a0; s < a1; ++s) {
    const float ws = w[s];
    const float2 f = *(const float2*)(node_h + (size_t)s * HDIM + h0);
    ax = fmaf(ws, fast_tanh(f.x), ax);
    ay = fmaf(ws, fast_tanh(f.y), ay);
  }
  atomicAdd(&pool[b * HDIM + h0], ax);
  atomicAdd(&pool[b * HDIM + h0 + 1], ay);
}

// code[b,:] = tanh( [tanh(tok_pool), tanh(ast_pool)] @ Wf + bf ); grid B
__global__ __launch_bounds__(256) void code_feat_kernel(
    const float* __restrict__ tok_pool, const float* __restrict__ ast_pool,
    const float* __restrict__ Wf, const float* __restrict__ bfv,
    float* __restrict__ code) {
  __shared__ float cat[2 * HDIM];
  const int b = blockIdx.x, tid = threadIdx.x;
  for (int i = tid; i < HDIM; i += 256) {
    cat[i] = fast_tanh(tok_pool[(size_t)b * HDIM + i]);
    cat[HDIM + i] = fast_tanh(ast_pool[(size_t)b * HDIM + i]);
  }
  __syncthreads();
  float acc0 = bfv[tid], acc1 = bfv[tid + 256];
  for (int k = 0; k < 2 * HDIM; ++k) {
    const float ck = cat[k];
    acc0 = fmaf(ck, Wf[(size_t)k * HDIM + tid], acc0);
    acc1 = fmaf(ck, Wf[(size_t)k * HDIM + tid + 256], acc1);
  }
  code[(size_t)b * HDIM + tid] = fast_tanh(acc0);
  code[(size_t)b * HDIM + tid + 256] = fast_tanh(acc1);
}

// per-sample hinge terms from cosine sims; grid B
__global__ __launch_bounds__(256) void sims_kernel(
    const float* __restrict__ code, const float* __restrict__ da_pool,
    const float* __restrict__ dn_pool, float* __restrict__ terms) {
  __shared__ float sr[4][5];
  const int b = blockIdx.x, tid = threadIdx.x;
  float c2 = 0, a2 = 0, n2 = 0, ca = 0, cn = 0;
  for (int i = tid; i < HDIM; i += 256) {
    const float cf = code[(size_t)b * HDIM + i];
    const float av = fast_tanh(fast_tanh(da_pool[(size_t)b * HDIM + i]));
    const float nv = fast_tanh(fast_tanh(dn_pool[(size_t)b * HDIM + i]));
    c2 = fmaf(cf, cf, c2); a2 = fmaf(av, av, a2); n2 = fmaf(nv, nv, n2);
    ca = fmaf(cf, av, ca); cn = fmaf(cf, nv, cn);
  }
#pragma unroll
  for (int off = 32; off; off >>= 1) {
    c2 += __shfl_xor(c2, off); a2 += __shfl_xor(a2, off); n2 += __shfl_xor(n2, off);
    ca += __shfl_xor(ca, off); cn += __shfl_xor(cn, off);
  }
  const int wv = tid >> 6;
  if ((tid & 63) == 0) {
    sr[wv][0] = c2; sr[wv][1] = a2; sr[wv][2] = n2; sr[wv][3] = ca; sr[wv][4] = cn;
  }
  __syncthreads();
  if (tid == 0) {
    c2 = sr[0][0] + sr[1][0] + sr[2][0] + sr[3][0];
    a2 = sr[0][1] + sr[1][1] + sr[2][1] + sr[3][1];
    n2 = sr[0][2] + sr[1][2] + sr[2][2] + sr[3][2];
    ca = sr[0][3] + sr[1][3] + sr[2][3] + sr[3][3];
    cn = sr[0][4] + sr[1][4] + sr[2][4] + sr[3][4];
    const float nc = fmaxf(sqrtf(c2), 1e-8f);
    const float na = fmaxf(sqrtf(a2), 1e-8f);
    const float nn = fmaxf(sqrtf(n2), 1e-8f);
    const float as = ca / (nc * na);
    const float ns = cn / (nc * nn);
    terms[b] = fmaxf(0.05f - as + ns, 1e-6f);
  }
}

__global__ void loss_kernel(const float* __restrict__ terms, float* __restrict__ out) {
  const int tid = threadIdx.x;  // 128 threads
  float v = terms[tid];
#pragma unroll
  for (int off = 32; off; off >>= 1) v += __shfl_xor(v, off);
  __shared__ float sr[2];
  if ((tid & 63) == 0) sr[tid >> 6] = v;
  __syncthreads();
  if (tid == 0) out[0] = (sr[0] + sr[1]) * (1.0f / (float)BATCH);
}

extern "C" void kernel_launch(void* const* d_in, const int* in_sizes, int n_in,
                              void* d_out, int out_size, void* d_ws, size_t ws_size,
                              hipStream_t stream) {
  (void)in_sizes; (void)n_in; (void)out_size; (void)ws_size;
  const float* token_feat = (const float*)d_in[0];
  const int*   token_len  = (const int*)d_in[1];
  const float* node_h     = (const float*)d_in[2];
  const int*   seg_ids    = (const int*)d_in[3];
  const float* da_feat    = (const float*)d_in[4];
  const int*   da_len     = (const int*)d_in[5];
  const float* dn_feat    = (const float*)d_in[6];
  const int*   dn_len     = (const int*)d_in[7];
  const float* Wt = (const float*)d_in[8];
  const float* bt = (const float*)d_in[9];
  const float* vt = (const float*)d_in[10];
  // d_in[11] = ct  (softmax-invariant constant, unused)
  const float* Wa = (const float*)d_in[12];
  const float* ba = (const float*)d_in[13];
  const float* va = (const float*)d_in[14];
  // d_in[15] = ca (unused)
  const float* Wd = (const float*)d_in[16];
  const float* bd = (const float*)d_in[17];
  const float* vd = (const float*)d_in[18];
  // d_in[19] = cd (unused)
  const float* Wf  = (const float*)d_in[20];
  const float* bfv = (const float*)d_in[21];

  const int MTOK = 128 * 512;   // 65536
  const int MDESC = 128 * 128;  // 16384
  const int NNODES = 65536;

  float* ws = (float*)d_ws;
  float* logits_tok  = ws;                     // 65536
  float* logits_node = logits_tok + MTOK;      // 65536
  float* logits_da   = logits_node + NNODES;   // 16384
  float* logits_dn   = logits_da + MDESC;      // 16384
  float* tok_pool    = logits_dn + MDESC;      // 65536
  float* ast_pool    = tok_pool + 128 * HDIM;  // 65536
  float* da_pool     = ast_pool + 128 * HDIM;  // 65536
  float* dn_pool     = da_pool + 128 * HDIM;   // 65536
  float* code        = dn_pool + 128 * HDIM;   // 65536
  float* terms       = code + 128 * HDIM;      // 128
  int*   seg_start   = (int*)(terms + 128);    // 129

  // zero all accumulation buffers (logits + pools are atomically accumulated)
  const int ZTOT = MTOK + NNODES + 2 * MDESC + 4 * 128 * HDIM;
  zero_kernel<<<dim3((ZTOT + 255) / 256), 256, 0, stream>>>(ws, ZTOT);
  seg_bounds_kernel<<<1, 256, 0, stream>>>(seg_ids, NNODES, seg_start);

  // fused logit GEMMs (the +c constants are softmax-invariant and skipped)
  gemm_logits_kernel<false><<<dim3(8, MTOK / 128), 256, 0, stream>>>(token_feat, Wt, bt, vt, logits_tok);
  gemm_logits_kernel<true ><<<dim3(8, NNODES / 128), 256, 0, stream>>>(node_h, Wa, ba, va, logits_node);
  gemm_logits_kernel<false><<<dim3(8, MDESC / 128), 256, 0, stream>>>(da_feat, Wd, bd, vd, logits_da);
  gemm_logits_kernel<false><<<dim3(8, MDESC / 128), 256, 0, stream>>>(dn_feat, Wd, bd, vd, logits_dn);

  softmax_masked_kernel<<<BATCH, 256, 0, stream>>>(logits_tok, token_len, 512);
  softmax_masked_kernel<<<BATCH, 256, 0, stream>>>(logits_da, da_len, 128);
  softmax_masked_kernel<<<BATCH, 256, 0, stream>>>(logits_dn, dn_len, 128);
  softmax_seg_kernel<<<BATCH, 256, 0, stream>>>(logits_node, seg_start);

  pool_masked_kernel<<<dim3(BATCH, 8), 256, 0, stream>>>(token_feat, logits_tok, tok_pool, 512, 64);
  pool_masked_kernel<<<dim3(BATCH, 2), 256, 0, stream>>>(da_feat, logits_da, da_pool, 128, 64);
  pool_masked_kernel<<<dim3(BATCH, 2), 256, 0, stream>>>(dn_feat, logits_dn, dn_pool, 128, 64);
  pool_seg_kernel<<<dim3(BATCH, 4), 256, 0, stream>>>(node_h, logits_node, seg_start, ast_pool);

  code_feat_kernel<<<BATCH, 256, 0, stream>>>(tok_pool, ast_pool, Wf, bfv, code);
  sims_kernel<<<BATCH, 256, 0, stream>>>(code, da_pool, dn_pool, terms);
  loss_kernel<<<1, 128, 0, stream>>>(terms, (float*)d_out);
}

// Round 2
// 564.304 us; speedup vs baseline: 2.6175x; 2.6175x over previous
//
#include <hip/hip_runtime.h>
#include <math.h>

#define HDIM 512
#define BATCH 128

typedef _Float16 f16x8 __attribute__((ext_vector_type(8)));
typedef _Float16 f16x4 __attribute__((ext_vector_type(4)));
typedef float f32x4 __attribute__((ext_vector_type(4)));

__device__ __forceinline__ float fast_tanh(float x) {
  float e = __expf(2.0f * x);
  return 1.0f - 2.0f / (e + 1.0f);
}

// ---------------------------------------------------------------------------
// W (fp32, [512 k][512 n]) -> Wt (f16, [512 n][512 k]). grid (8,8), 256 thr.
// ---------------------------------------------------------------------------
__global__ __launch_bounds__(256) void transpose_w_kernel(
    const float* __restrict__ W, _Float16* __restrict__ Wt) {
  __shared__ float tile[64][65];
  const int bk = blockIdx.x * 64, bn = blockIdx.y * 64;
  const int txl = threadIdx.x & 63, tyl = threadIdx.x >> 6;
#pragma unroll
  for (int r = tyl; r < 64; r += 4)
    tile[r][txl] = W[(size_t)(bk + r) * HDIM + bn + txl];
  __syncthreads();
#pragma unroll
  for (int r = tyl; r < 64; r += 4)
    Wt[(size_t)(bn + r) * HDIM + bk + txl] = (_Float16)tile[txl][r];
}

// ---------------------------------------------------------------------------
// Fused logit GEMM via f16 MFMA:
//   logits[m] += sum_n v[n] * tanh( (A@W)[m,n] + bias[n] )
// A: M x 512 fp32 (tanh'd on load if TANH_IN); Wt: f16 [n][k] (pre-transposed).
// Block: 128(M) x 256(N), BK=64, 512 threads = 8 waves (4M x 2N),
// wave tile 32x128 via 2x8 fragments of mfma_f32_16x16x32_f16.
// LDS XOR-swizzle (byte ^= (row&7)<<4) keeps ds_read_b128 conflict-free.
// grid: 1-D, nb fastest; XCD-bijective swizzle pairs the 2 n-blocks that
// share an A-panel onto one XCD for L2 reuse. logits must be pre-zeroed.
// ---------------------------------------------------------------------------
template <bool TANH_IN>
__global__ __launch_bounds__(512) void gemm_logits_mfma_kernel(
    const float* __restrict__ A, const _Float16* __restrict__ Wt,
    const float* __restrict__ bias, const float* __restrict__ vvec,
    float* __restrict__ logits) {
  __shared__ __align__(16) _Float16 As[128 * 64];
  __shared__ __align__(16) _Float16 Bs[256 * 64];

  const int tid = threadIdx.x;
  // XCD-aware bijective swizzle (all grids here are %8==0)
  const int nwg = gridDim.x;
  const int qq = nwg >> 3;
  const int raw = blockIdx.x;
  const int swz = (raw & 7) * qq + (raw >> 3);
  const int nb = swz & 1;
  const int mb = swz >> 1;
  const int m0 = mb * 128;
  const int n0 = nb * 256;

  const int lane = tid & 63;
  const int tx = lane & 15;   // fragment row/col within 16
  const int qd = lane >> 4;   // k-quad / output row-quad
  const int wid = tid >> 6;   // 0..7
  const int wm = wid >> 1;    // 0..3 -> rows wm*32..+31
  const int wn = wid & 1;     // 0..1 -> cols wn*128..+127

  // staging coords
  const int rA = tid >> 4;        // 0..31 (A row per pass)
  const int cA = (tid & 15) * 4;  // A float col
  const int rB = tid >> 3;        // 0..63 (B n-row per pass)
  const int cB = (tid & 7) * 8;   // B f16 col (k)

  f32x4 acc[2][8];
#pragma unroll
  for (int i = 0; i < 2; ++i)
#pragma unroll
    for (int j = 0; j < 8; ++j) acc[i][j] = (f32x4){0.f, 0.f, 0.f, 0.f};

  for (int k0 = 0; k0 < HDIM; k0 += 64) {
    // --- stage A: 128x64 fp32 -> f16 (swizzled) ---
#pragma unroll
    for (int p = 0; p < 4; ++p) {
      const int r = rA + p * 32;
      float4 a = *(const float4*)(A + (size_t)(m0 + r) * HDIM + k0 + cA);
      if (TANH_IN) {
        a.x = fast_tanh(a.x); a.y = fast_tanh(a.y);
        a.z = fast_tanh(a.z); a.w = fast_tanh(a.w);
      }
      f16x4 h;
      h[0] = (_Float16)a.x; h[1] = (_Float16)a.y;
      h[2] = (_Float16)a.z; h[3] = (_Float16)a.w;
      int byte = r * 128 + cA * 2;
      byte ^= (r & 7) << 4;
      *(f16x4*)((char*)As + byte) = h;
    }
    // --- stage B: 256x64 f16 rows of Wt (swizzled) ---
#pragma unroll
    for (int p = 0; p < 4; ++p) {
      const int n = rB + p * 64;
      f16x8 w = *(const f16x8*)(Wt + (size_t)(n0 + n) * HDIM + k0 + cB);
      int byte = n * 128 + cB * 2;
      byte ^= (n & 7) << 4;
      *(f16x8*)((char*)Bs + byte) = w;
    }
    __syncthreads();
#pragma unroll
    for (int ks = 0; ks < 2; ++ks) {
      f16x8 aF[2];
#pragma unroll
      for (int fm = 0; fm < 2; ++fm) {
        const int row = wm * 32 + fm * 16 + tx;
        int byte = row * 128 + (ks * 32 + qd * 8) * 2;
        byte ^= (row & 7) << 4;
        aF[fm] = *(const f16x8*)((const char*)As + byte);
      }
#pragma unroll
      for (int fn = 0; fn < 8; ++fn) {
        const int n = wn * 128 + fn * 16 + tx;
        int byte = n * 128 + (ks * 32 + qd * 8) * 2;
        byte ^= (n & 7) << 4;
        const f16x8 bF = *(const f16x8*)((const char*)Bs + byte);
        acc[0][fn] = __builtin_amdgcn_mfma_f32_16x16x32_f16(aF[0], bF, acc[0][fn], 0, 0, 0);
        acc[1][fn] = __builtin_amdgcn_mfma_f32_16x16x32_f16(aF[1], bF, acc[1][fn], 0, 0, 0);
      }
    }
    __syncthreads();
  }

  // --- epilogue: t = tanh(acc + bias[n]) * v[n], reduce over this block's n ---
  float vv[8], bb[8];
#pragma unroll
  for (int fn = 0; fn < 8; ++fn) {
    const int n = n0 + wn * 128 + fn * 16 + tx;
    vv[fn] = vvec[n];
    bb[fn] = bias[n];
  }
#pragma unroll
  for (int fm = 0; fm < 2; ++fm) {
#pragma unroll
    for (int r = 0; r < 4; ++r) {
      float s = 0.0f;
#pragma unroll
      for (int fn = 0; fn < 8; ++fn)
        s = fmaf(vv[fn], fast_tanh(acc[fm][fn][r] + bb[fn]), s);
      s += __shfl_xor(s, 1);
      s += __shfl_xor(s, 2);
      s += __shfl_xor(s, 4);
      s += __shfl_xor(s, 8);
      if (tx == 0)
        atomicAdd(&logits[m0 + wm * 32 + fm * 16 + qd * 4 + r], s);
    }
  }
}

__global__ void zero_kernel(float* __restrict__ p, int n) {
  const int i = blockIdx.x * 256 + threadIdx.x;
  if (i < n) p[i] = 0.0f;
}

__global__ void seg_bounds_kernel(const int* __restrict__ seg, int N,
                                  int* __restrict__ seg_start) {
  const int b = threadIdx.x;
  if (b > BATCH) return;
  int lo = 0, hi = N;
  while (lo < hi) {
    const int mid = (lo + hi) >> 1;
    if (seg[mid] < b) lo = mid + 1; else hi = mid;
  }
  seg_start[b] = lo;
}

__global__ __launch_bounds__(256) void softmax_masked_kernel(
    float* __restrict__ logits, const int* __restrict__ lens, int S) {
  __shared__ float smax[4], ssum[4];
  const int b = blockIdx.x, tid = threadIdx.x;
  const int len = lens[b];
  float* l = logits + (size_t)b * S;
  float mymax = -1e30f;
  for (int s = tid; s < len; s += 256) mymax = fmaxf(mymax, l[s]);
#pragma unroll
  for (int off = 32; off; off >>= 1) mymax = fmaxf(mymax, __shfl_xor(mymax, off));
  if ((tid & 63) == 0) smax[tid >> 6] = mymax;
  __syncthreads();
  const float bmax = fmaxf(fmaxf(smax[0], smax[1]), fmaxf(smax[2], smax[3]));
  float mysum = 0.0f;
  for (int s = tid; s < len; s += 256) mysum += __expf(l[s] - bmax);
#pragma unroll
  for (int off = 32; off; off >>= 1) mysum += __shfl_xor(mysum, off);
  if ((tid & 63) == 0) ssum[tid >> 6] = mysum;
  __syncthreads();
  const float inv = 1.0f / (ssum[0] + ssum[1] + ssum[2] + ssum[3]);
  for (int s = tid; s < S; s += 256)
    l[s] = (s < len) ? __expf(l[s] - bmax) * inv : 0.0f;
}

__global__ __launch_bounds__(256) void softmax_seg_kernel(
    float* __restrict__ logits, const int* __restrict__ seg_start) {
  __shared__ float smax[4], ssum[4];
  const int b = blockIdx.x, tid = threadIdx.x;
  const int s0 = seg_start[b], s1 = seg_start[b + 1];
  float mymax = -1e30f;
  for (int s = s0 + tid; s < s1; s += 256) mymax = fmaxf(mymax, logits[s]);
#pragma unroll
  for (int off = 32; off; off >>= 1) mymax = fmaxf(mymax, __shfl_xor(mymax, off));
  if ((tid & 63) == 0) smax[tid >> 6] = mymax;
  __syncthreads();
  const float bmax = fmaxf(fmaxf(smax[0], smax[1]), fmaxf(smax[2], smax[3]));
  float mysum = 0.0f;
  for (int s = s0 + tid; s < s1; s += 256) mysum += __expf(logits[s] - bmax);
#pragma unroll
  for (int off = 32; off; off >>= 1) mysum += __shfl_xor(mysum, off);
  if ((tid & 63) == 0) ssum[tid >> 6] = mysum;
  __syncthreads();
  const float inv = 1.0f / (ssum[0] + ssum[1] + ssum[2] + ssum[3]);
  for (int s = s0 + tid; s < s1; s += 256)
    logits[s] = __expf(logits[s] - bmax) * inv;
}

__global__ __launch_bounds__(256) void pool_masked_kernel(
    const float* __restrict__ feat, const float* __restrict__ w,
    float* __restrict__ pool, int S, int chunk) {
  const int b = blockIdx.x, c = blockIdx.y, tid = threadIdx.x;
  const int h0 = tid * 2;
  const int s0 = c * chunk;
  const int s1 = min(S, s0 + chunk);
  const float* fb = feat + (size_t)b * S * HDIM;
  const float* wb = w + (size_t)b * S;
  float ax = 0.0f, ay = 0.0f;
  for (int s = s0; s < s1; ++s) {
    const float ws = wb[s];
    if (ws != 0.0f) {
      const float2 f = *(const float2*)(fb + (size_t)s * HDIM + h0);
      ax = fmaf(ws, f.x, ax);
      ay = fmaf(ws, f.y, ay);
    }
  }
  atomicAdd(&pool[b * HDIM + h0], ax);
  atomicAdd(&pool[b * HDIM + h0 + 1], ay);
}

__global__ __launch_bounds__(256) void pool_seg_kernel(
    const float* __restrict__ node_h, const float* __restrict__ w,
    const int* __restrict__ seg_start, float* __restrict__ pool) {
  const int b = blockIdx.x, c = blockIdx.y, tid = threadIdx.x;
  const int h0 = tid * 2;
  const int s0 = seg_start[b], s1 = seg_start[b + 1];
  const int nseg = s1 - s0;
  const int chunk = (nseg + (int)gridDim.y - 1) / (int)gridDim.y;
  const int a0 = s0 + c * chunk;
  const int a1 = min(s1, a0 + chunk);
  float ax = 0.0f, ay = 0.0f;
  for (int s = a0; s < a1; ++s) {
    const float ws = w[s];
    const float2 f = *(const float2*)(node_h + (size_t)s * HDIM + h0);
    ax = fmaf(ws, fast_tanh(f.x), ax);
    ay = fmaf(ws, fast_tanh(f.y), ay);
  }
  atomicAdd(&pool[b * HDIM + h0], ax);
  atomicAdd(&pool[b * HDIM + h0 + 1], ay);
}

__global__ __launch_bounds__(256) void code_feat_kernel(
    const float* __restrict__ tok_pool, const float* __restrict__ ast_pool,
    const float* __restrict__ Wf, const float* __restrict__ bfv,
    float* __restrict__ code) {
  __shared__ float cat[2 * HDIM];
  const int b = blockIdx.x, tid = threadIdx.x;
  for (int i = tid; i < HDIM; i += 256) {
    cat[i] = fast_tanh(tok_pool[(size_t)b * HDIM + i]);
    cat[HDIM + i] = fast_tanh(ast_pool[(size_t)b * HDIM + i]);
  }
  __syncthreads();
  float acc0 = bfv[tid], acc1 = bfv[tid + 256];
  for (int k = 0; k < 2 * HDIM; ++k) {
    const float ck = cat[k];
    acc0 = fmaf(ck, Wf[(size_t)k * HDIM + tid], acc0);
    acc1 = fmaf(ck, Wf[(size_t)k * HDIM + tid + 256], acc1);
  }
  code[(size_t)b * HDIM + tid] = fast_tanh(acc0);
  code[(size_t)b * HDIM + tid + 256] = fast_tanh(acc1);
}

__global__ __launch_bounds__(256) void sims_kernel(
    const float* __restrict__ code, const float* __restrict__ da_pool,
    const float* __restrict__ dn_pool, float* __restrict__ terms) {
  __shared__ float sr[4][5];
  const int b = blockIdx.x, tid = threadIdx.x;
  float c2 = 0, a2 = 0, n2 = 0, ca = 0, cn = 0;
  for (int i = tid; i < HDIM; i += 256) {
    const float cf = code[(size_t)b * HDIM + i];
    const float av = fast_tanh(fast_tanh(da_pool[(size_t)b * HDIM + i]));
    const float nv = fast_tanh(fast_tanh(dn_pool[(size_t)b * HDIM + i]));
    c2 = fmaf(cf, cf, c2); a2 = fmaf(av, av, a2); n2 = fmaf(nv, nv, n2);
    ca = fmaf(cf, av, ca); cn = fmaf(cf, nv, cn);
  }
#pragma unroll
  for (int off = 32; off; off >>= 1) {
    c2 += __shfl_xor(c2, off); a2 += __shfl_xor(a2, off); n2 += __shfl_xor(n2, off);
    ca += __shfl_xor(ca, off); cn += __shfl_xor(cn, off);
  }
  const int wv = tid >> 6;
  if ((tid & 63) == 0) {
    sr[wv][0] = c2; sr[wv][1] = a2; sr[wv][2] = n2; sr[wv][3] = ca; sr[wv][4] = cn;
  }
  __syncthreads();
  if (tid == 0) {
    c2 = sr[0][0] + sr[1][0] + sr[2][0] + sr[3][0];
    a2 = sr[0][1] + sr[1][1] + sr[2][1] + sr[3][1];
    n2 = sr[0][2] + sr[1][2] + sr[2][2] + sr[3][2];
    ca = sr[0][3] + sr[1][3] + sr[2][3] + sr[3][3];
    cn = sr[0][4] + sr[1][4] + sr[2][4] + sr[3][4];
    const float nc = fmaxf(sqrtf(c2), 1e-8f);
    const float na = fmaxf(sqrtf(a2), 1e-8f);
    const float nn = fmaxf(sqrtf(n2), 1e-8f);
    const float as = ca / (nc * na);
    const float ns = cn / (nc * nn);
    terms[b] = fmaxf(0.05f - as + ns, 1e-6f);
  }
}

__global__ void loss_kernel(const float* __restrict__ terms, float* __restrict__ out) {
  const int tid = threadIdx.x;  // 128 threads
  float v = terms[tid];
#pragma unroll
  for (int off = 32; off; off >>= 1) v += __shfl_xor(v, off);
  __shared__ float sr[2];
  if ((tid & 63) == 0) sr[tid >> 6] = v;
  __syncthreads();
  if (tid == 0) out[0] = (sr[0] + sr[1]) * (1.0f / (float)BATCH);
}

extern "C" void kernel_launch(void* const* d_in, const int* in_sizes, int n_in,
                              void* d_out, int out_size, void* d_ws, size_t ws_size,
                              hipStream_t stream) {
  (void)in_sizes; (void)n_in; (void)out_size; (void)ws_size;
  const float* token_feat = (const float*)d_in[0];
  const int*   token_len  = (const int*)d_in[1];
  const float* node_h     = (const float*)d_in[2];
  const int*   seg_ids    = (const int*)d_in[3];
  const float* da_feat    = (const float*)d_in[4];
  const int*   da_len     = (const int*)d_in[5];
  const float* dn_feat    = (const float*)d_in[6];
  const int*   dn_len     = (const int*)d_in[7];
  const float* Wt = (const float*)d_in[8];
  const float* bt = (const float*)d_in[9];
  const float* vt = (const float*)d_in[10];
  const float* Wa = (const float*)d_in[12];
  const float* ba = (const float*)d_in[13];
  const float* va = (const float*)d_in[14];
  const float* Wd = (const float*)d_in[16];
  const float* bd = (const float*)d_in[17];
  const float* vd = (const float*)d_in[18];
  const float* Wf  = (const float*)d_in[20];
  const float* bfv = (const float*)d_in[21];

  const int MTOK = 128 * 512;   // 65536
  const int MDESC = 128 * 128;  // 16384
  const int NNODES = 65536;

  float* ws = (float*)d_ws;
  float* logits_tok  = ws;                     // 65536
  float* logits_node = logits_tok + MTOK;      // 65536
  float* logits_da   = logits_node + NNODES;   // 16384
  float* logits_dn   = logits_da + MDESC;      // 16384
  float* tok_pool    = logits_dn + MDESC;      // 65536
  float* ast_pool    = tok_pool + 128 * HDIM;  // 65536
  float* da_pool     = ast_pool + 128 * HDIM;  // 65536
  float* dn_pool     = da_pool + 128 * HDIM;   // 65536
  float* code        = dn_pool + 128 * HDIM;   // 65536
  float* terms       = code + 128 * HDIM;      // 128
  int*   seg_start   = (int*)(terms + 128);    // 129 (+pad)
  _Float16* Wt_t = (_Float16*)(seg_start + 256);         // 512*512 f16
  _Float16* Wa_t = Wt_t + HDIM * HDIM;
  _Float16* Wd_t = Wa_t + HDIM * HDIM;

  // zero accumulation buffers (logits + pools)
  const int ZTOT = MTOK + NNODES + 2 * MDESC + 4 * 128 * HDIM;
  zero_kernel<<<dim3((ZTOT + 255) / 256), 256, 0, stream>>>(ws, ZTOT);
  seg_bounds_kernel<<<1, 256, 0, stream>>>(seg_ids, NNODES, seg_start);
  transpose_w_kernel<<<dim3(8, 8), 256, 0, stream>>>(Wt, Wt_t);
  transpose_w_kernel<<<dim3(8, 8), 256, 0, stream>>>(Wa, Wa_t);
  transpose_w_kernel<<<dim3(8, 8), 256, 0, stream>>>(Wd, Wd_t);

  // fused logit GEMMs via f16 MFMA (the +c constants are softmax-invariant)
  gemm_logits_mfma_kernel<false><<<MTOK / 128 * 2, 512, 0, stream>>>(token_feat, Wt_t, bt, vt, logits_tok);
  gemm_logits_mfma_kernel<true ><<<NNODES / 128 * 2, 512, 0, stream>>>(node_h, Wa_t, ba, va, logits_node);
  gemm_logits_mfma_kernel<false><<<MDESC / 128 * 2, 512, 0, stream>>>(da_feat, Wd_t, bd, vd, logits_da);
  gemm_logits_mfma_kernel<false><<<MDESC / 128 * 2, 512, 0, stream>>>(dn_feat, Wd_t, bd, vd, logits_dn);

  softmax_masked_kernel<<<BATCH, 256, 0, stream>>>(logits_tok, token_len, 512);
  softmax_masked_kernel<<<BATCH, 256, 0, stream>>>(logits_da, da_len, 128);
  softmax_masked_kernel<<<BATCH, 256, 0, stream>>>(logits_dn, dn_len, 128);
  softmax_seg_kernel<<<BATCH, 256, 0, stream>>>(logits_node, seg_start);

  pool_masked_kernel<<<dim3(BATCH, 8), 256, 0, stream>>>(token_feat, logits_tok, tok_pool, 512, 64);
  pool_masked_kernel<<<dim3(BATCH, 2), 256, 0, stream>>>(da_feat, logits_da, da_pool, 128, 64);
  pool_masked_kernel<<<dim3(BATCH, 2), 256, 0, stream>>>(dn_feat, logits_dn, dn_pool, 128, 64);
  pool_seg_kernel<<<dim3(BATCH, 4), 256, 0, stream>>>(node_h, logits_node, seg_start, ast_pool);

  code_feat_kernel<<<BATCH, 256, 0, stream>>>(tok_pool, ast_pool, Wf, bfv, code);
  sims_kernel<<<BATCH, 256, 0, stream>>>(code, da_pool, dn_pool, terms);
  loss_kernel<<<1, 128, 0, stream>>>(terms, (float*)d_out);
}

// Round 3
// 469.530 us; speedup vs baseline: 3.1459x; 1.2018x over previous
//
#include <hip/hip_runtime.h>
#include <math.h>

#define HDIM 512
#define BATCH 128

typedef _Float16 f16x8 __attribute__((ext_vector_type(8)));
typedef _Float16 f16x4 __attribute__((ext_vector_type(4)));
typedef float f32x4 __attribute__((ext_vector_type(4)));

__device__ __forceinline__ float fast_tanh(float x) {
  float e = __expf(2.0f * x);
  return 1.0f - 2.0f / (e + 1.0f);
}

__device__ __forceinline__ void gload_lds16(const void* g, void* l) {
  __builtin_amdgcn_global_load_lds(
      (const __attribute__((address_space(1))) unsigned int*)g,
      (__attribute__((address_space(3))) unsigned int*)l, 16, 0, 0);
}

// ===========================================================================
// FAST PATH kernels (need ~172 MB workspace)
// ===========================================================================

// A [M][512] fp32 -> A2 [8 kt][M][64] f16, rows XOR-swizzled (byte ^= (m&7)<<4)
// so that linear global_load_lds staging + swizzled ds_read is conflict-free.
template <bool TANH>
__global__ __launch_bounds__(256) void cvt_tile_kernel(
    const float* __restrict__ A, _Float16* __restrict__ A2, int M) {
  const int total = M * 64;  // 16B chunks
  for (int i = blockIdx.x * 256 + threadIdx.x; i < total; i += gridDim.x * 256) {
    const int m = i >> 6, c = i & 63;
    const int kt = c >> 3, cc = c & 7;
    const float* src = A + (size_t)m * HDIM + c * 8;
    const float4 x = ((const float4*)src)[0];
    const float4 y = ((const float4*)src)[1];
    f16x8 h;
    if (TANH) {
      h[0] = (_Float16)fast_tanh(x.x); h[1] = (_Float16)fast_tanh(x.y);
      h[2] = (_Float16)fast_tanh(x.z); h[3] = (_Float16)fast_tanh(x.w);
      h[4] = (_Float16)fast_tanh(y.x); h[5] = (_Float16)fast_tanh(y.y);
      h[6] = (_Float16)fast_tanh(y.z); h[7] = (_Float16)fast_tanh(y.w);
    } else {
      h[0] = (_Float16)x.x; h[1] = (_Float16)x.y;
      h[2] = (_Float16)x.z; h[3] = (_Float16)x.w;
      h[4] = (_Float16)y.x; h[5] = (_Float16)y.y;
      h[6] = (_Float16)y.z; h[7] = (_Float16)y.w;
    }
    char* dst = (char*)A2 + ((size_t)kt * M + m) * 128 + ((cc * 16) ^ ((m & 7) << 4));
    *(f16x8*)dst = h;
  }
}

// W [512 k][512 n] fp32 -> W2 [8 kt][512 n][64 k] f16, rows XOR-swizzled by n.
__global__ __launch_bounds__(256) void cvt_w_kernel(
    const float* __restrict__ W, _Float16* __restrict__ W2) {
  const int i = blockIdx.x * 256 + threadIdx.x;  // 512*64 = 32768 items
  if (i >= 512 * 64) return;
  const int n = i & 511, g = i >> 9;
  const int kt = g >> 3, cc = g & 7;
  f16x8 h;
#pragma unroll
  for (int j = 0; j < 8; ++j)
    h[j] = (_Float16)W[(size_t)(kt * 64 + cc * 8 + j) * HDIM + n];
  char* dst = (char*)W2 + ((size_t)kt * 512 + n) * 128 + ((cc * 16) ^ ((n & 7) << 4));
  *(f16x8*)dst = h;
}

// ---------------------------------------------------------------------------
// Fused logit GEMM, all-f16 operands, global_load_lds staging (m97 recipe):
//   logits[m] += sum_n v[n] * tanh( (A@W)[m,n] + bias[n] )
// A2: [8][M][64] swizzled f16; W2: [8][512][64] swizzled f16.
// Block 128(M) x 256(N), BK=64, 512 thr = 8 waves (4M x 2N), wave tile 32x128.
// ---------------------------------------------------------------------------
__global__ __launch_bounds__(512) void gemm_logits_f16_kernel(
    const _Float16* __restrict__ A2, const _Float16* __restrict__ W2,
    const float* __restrict__ bias, const float* __restrict__ vvec,
    float* __restrict__ logits, int M) {
  __shared__ __align__(16) _Float16 As[128 * 64];  // 16 KB
  __shared__ __align__(16) _Float16 Bs[256 * 64];  // 32 KB

  const int tid = threadIdx.x;
  const int nwg = gridDim.x;
  const int qq = nwg >> 3;
  const int raw = blockIdx.x;
  const int swz = (raw & 7) * qq + (raw >> 3);  // XCD-bijective (nwg%8==0)
  const int nb = swz & 1;
  const int mb = swz >> 1;
  const size_t m0 = (size_t)mb * 128;
  const int n0 = nb * 256;

  const int lane = tid & 63;
  const int wid = tid >> 6;
  const int tx = lane & 15;
  const int qd = lane >> 4;
  const int wm = wid >> 1;
  const int wn = wid & 1;

  f32x4 acc[2][8];
#pragma unroll
  for (int i = 0; i < 2; ++i)
#pragma unroll
    for (int j = 0; j < 8; ++j) acc[i][j] = (f32x4){0.f, 0.f, 0.f, 0.f};

  const char* gA = (const char*)A2 + m0 * 128;
  const char* gB = (const char*)W2 + (size_t)n0 * 128;
  const size_t strideA = (size_t)M * 128;
  const size_t strideB = (size_t)512 * 128;
  const int wlo = wid * 1024;        // wave-uniform LDS base
  const int glo = wlo + lane * 16;   // per-lane global offset

  for (int kt = 0; kt < 8; ++kt) {
    const char* a = gA + (size_t)kt * strideA;
    const char* b = gB + (size_t)kt * strideB;
    gload_lds16(a + glo,         (char*)As + wlo);
    gload_lds16(a + glo + 8192,  (char*)As + wlo + 8192);
    gload_lds16(b + glo,         (char*)Bs + wlo);
    gload_lds16(b + glo + 8192,  (char*)Bs + wlo + 8192);
    gload_lds16(b + glo + 16384, (char*)Bs + wlo + 16384);
    gload_lds16(b + glo + 24576, (char*)Bs + wlo + 24576);
    __syncthreads();  // drains vmcnt + barrier
#pragma unroll
    for (int ks = 0; ks < 2; ++ks) {
      f16x8 aF[2];
#pragma unroll
      for (int fm = 0; fm < 2; ++fm) {
        const int row = wm * 32 + fm * 16 + tx;
        int byte = row * 128 + (ks * 32 + qd * 8) * 2;
        byte ^= (row & 7) << 4;
        aF[fm] = *(const f16x8*)((const char*)As + byte);
      }
#pragma unroll
      for (int fn = 0; fn < 8; ++fn) {
        const int n = wn * 128 + fn * 16 + tx;
        int byte = n * 128 + (ks * 32 + qd * 8) * 2;
        byte ^= (n & 7) << 4;
        const f16x8 bF = *(const f16x8*)((const char*)Bs + byte);
        acc[0][fn] = __builtin_amdgcn_mfma_f32_16x16x32_f16(aF[0], bF, acc[0][fn], 0, 0, 0);
        acc[1][fn] = __builtin_amdgcn_mfma_f32_16x16x32_f16(aF[1], bF, acc[1][fn], 0, 0, 0);
      }
    }
    __syncthreads();
  }

  float vv[8], bb[8];
#pragma unroll
  for (int fn = 0; fn < 8; ++fn) {
    const int n = n0 + wn * 128 + fn * 16 + tx;
    vv[fn] = vvec[n];
    bb[fn] = bias[n];
  }
#pragma unroll
  for (int fm = 0; fm < 2; ++fm) {
#pragma unroll
    for (int r = 0; r < 4; ++r) {
      float s = 0.0f;
#pragma unroll
      for (int fn = 0; fn < 8; ++fn)
        s = fmaf(vv[fn], fast_tanh(acc[fm][fn][r] + bb[fn]), s);
      s += __shfl_xor(s, 1);
      s += __shfl_xor(s, 2);
      s += __shfl_xor(s, 4);
      s += __shfl_xor(s, 8);
      if (tx == 0)
        atomicAdd(&logits[m0 + wm * 32 + fm * 16 + qd * 4 + r], s);
    }
  }
}

// pool[b,h] += sum_s w[b,s] * A2f16[row=b*S+s, h]; A2 tiled-swizzled layout.
__global__ __launch_bounds__(256) void pool_tiled_masked_kernel(
    const _Float16* __restrict__ A2, const float* __restrict__ w,
    float* __restrict__ pool, int Mtot, int S, int chunk) {
  const int b = blockIdx.x, c = blockIdx.y, tid = threadIdx.x;
  const int h = tid * 2;
  const int kt = h >> 6, col = h & 63;
  const char* base = (const char*)A2 + (size_t)kt * Mtot * 128;
  const float* wb = w + (size_t)b * S;
  const int s0 = c * chunk, s1 = min(S, s0 + chunk);
  float ax = 0.0f, ay = 0.0f;
  for (int s = s0; s < s1; ++s) {
    const float ws = wb[s];
    if (ws != 0.0f) {
      const size_t m = (size_t)b * S + s;
      const unsigned u = *(const unsigned*)(base + m * 128 + ((col * 2) ^ (((int)m & 7) << 4)));
      const _Float16* hp = (const _Float16*)&u;
      ax = fmaf(ws, (float)hp[0], ax);
      ay = fmaf(ws, (float)hp[1], ay);
    }
  }
  atomicAdd(&pool[b * HDIM + h], ax);
  atomicAdd(&pool[b * HDIM + h + 1], ay);
}

// ast_pool[b,h] += sum_{n in seg b} w[n] * A2node[n, h] (tanh pre-applied).
__global__ __launch_bounds__(256) void pool_tiled_seg_kernel(
    const _Float16* __restrict__ A2, const float* __restrict__ w,
    const int* __restrict__ seg_start, float* __restrict__ pool, int Mtot) {
  const int b = blockIdx.x, c = blockIdx.y, tid = threadIdx.x;
  const int h = tid * 2;
  const int kt = h >> 6, col = h & 63;
  const char* base = (const char*)A2 + (size_t)kt * Mtot * 128;
  const int s0 = seg_start[b], s1 = seg_start[b + 1];
  const int nseg = s1 - s0;
  const int chunk = (nseg + (int)gridDim.y - 1) / (int)gridDim.y;
  const int a0 = s0 + c * chunk;
  const int a1 = min(s1, a0 + chunk);
  float ax = 0.0f, ay = 0.0f;
  for (int s = a0; s < a1; ++s) {
    const float ws = w[s];
    const unsigned u = *(const unsigned*)(base + (size_t)s * 128 + ((col * 2) ^ ((s & 7) << 4)));
    const _Float16* hp = (const _Float16*)&u;
    ax = fmaf(ws, (float)hp[0], ax);
    ay = fmaf(ws, (float)hp[1], ay);
  }
  atomicAdd(&pool[b * HDIM + h], ax);
  atomicAdd(&pool[b * HDIM + h + 1], ay);
}

// ===========================================================================
// FALLBACK PATH kernels (R2, used if workspace too small)
// ===========================================================================

__global__ __launch_bounds__(256) void transpose_w_kernel(
    const float* __restrict__ W, _Float16* __restrict__ Wt) {
  __shared__ float tile[64][65];
  const int bk = blockIdx.x * 64, bn = blockIdx.y * 64;
  const int txl = threadIdx.x & 63, tyl = threadIdx.x >> 6;
#pragma unroll
  for (int r = tyl; r < 64; r += 4)
    tile[r][txl] = W[(size_t)(bk + r) * HDIM + bn + txl];
  __syncthreads();
#pragma unroll
  for (int r = tyl; r < 64; r += 4)
    Wt[(size_t)(bn + r) * HDIM + bk + txl] = (_Float16)tile[txl][r];
}

template <bool TANH_IN>
__global__ __launch_bounds__(512) void gemm_logits_mfma_kernel(
    const float* __restrict__ A, const _Float16* __restrict__ Wt,
    const float* __restrict__ bias, const float* __restrict__ vvec,
    float* __restrict__ logits) {
  __shared__ __align__(16) _Float16 As[128 * 64];
  __shared__ __align__(16) _Float16 Bs[256 * 64];
  const int tid = threadIdx.x;
  const int nwg = gridDim.x;
  const int qq = nwg >> 3;
  const int raw = blockIdx.x;
  const int swz = (raw & 7) * qq + (raw >> 3);
  const int nb = swz & 1;
  const int mb = swz >> 1;
  const int m0 = mb * 128;
  const int n0 = nb * 256;
  const int lane = tid & 63;
  const int tx = lane & 15;
  const int qd = lane >> 4;
  const int wid = tid >> 6;
  const int wm = wid >> 1;
  const int wn = wid & 1;
  const int rA = tid >> 4;
  const int cA = (tid & 15) * 4;
  const int rB = tid >> 3;
  const int cB = (tid & 7) * 8;
  f32x4 acc[2][8];
#pragma unroll
  for (int i = 0; i < 2; ++i)
#pragma unroll
    for (int j = 0; j < 8; ++j) acc[i][j] = (f32x4){0.f, 0.f, 0.f, 0.f};
  for (int k0 = 0; k0 < HDIM; k0 += 64) {
#pragma unroll
    for (int p = 0; p < 4; ++p) {
      const int r = rA + p * 32;
      float4 a = *(const float4*)(A + (size_t)(m0 + r) * HDIM + k0 + cA);
      if (TANH_IN) {
        a.x = fast_tanh(a.x); a.y = fast_tanh(a.y);
        a.z = fast_tanh(a.z); a.w = fast_tanh(a.w);
      }
      f16x4 h;
      h[0] = (_Float16)a.x; h[1] = (_Float16)a.y;
      h[2] = (_Float16)a.z; h[3] = (_Float16)a.w;
      int byte = r * 128 + cA * 2;
      byte ^= (r & 7) << 4;
      *(f16x4*)((char*)As + byte) = h;
    }
#pragma unroll
    for (int p = 0; p < 4; ++p) {
      const int n = rB + p * 64;
      f16x8 w = *(const f16x8*)(Wt + (size_t)(n0 + n) * HDIM + k0 + cB);
      int byte = n * 128 + cB * 2;
      byte ^= (n & 7) << 4;
      *(f16x8*)((char*)Bs + byte) = w;
    }
    __syncthreads();
#pragma unroll
    for (int ks = 0; ks < 2; ++ks) {
      f16x8 aF[2];
#pragma unroll
      for (int fm = 0; fm < 2; ++fm) {
        const int row = wm * 32 + fm * 16 + tx;
        int byte = row * 128 + (ks * 32 + qd * 8) * 2;
        byte ^= (row & 7) << 4;
        aF[fm] = *(const f16x8*)((const char*)As + byte);
      }
#pragma unroll
      for (int fn = 0; fn < 8; ++fn) {
        const int n = wn * 128 + fn * 16 + tx;
        int byte = n * 128 + (ks * 32 + qd * 8) * 2;
        byte ^= (n & 7) << 4;
        const f16x8 bF = *(const f16x8*)((const char*)Bs + byte);
        acc[0][fn] = __builtin_amdgcn_mfma_f32_16x16x32_f16(aF[0], bF, acc[0][fn], 0, 0, 0);
        acc[1][fn] = __builtin_amdgcn_mfma_f32_16x16x32_f16(aF[1], bF, acc[1][fn], 0, 0, 0);
      }
    }
    __syncthreads();
  }
  float vv[8], bb[8];
#pragma unroll
  for (int fn = 0; fn < 8; ++fn) {
    const int n = n0 + wn * 128 + fn * 16 + tx;
    vv[fn] = vvec[n];
    bb[fn] = bias[n];
  }
#pragma unroll
  for (int fm = 0; fm < 2; ++fm) {
#pragma unroll
    for (int r = 0; r < 4; ++r) {
      float s = 0.0f;
#pragma unroll
      for (int fn = 0; fn < 8; ++fn)
        s = fmaf(vv[fn], fast_tanh(acc[fm][fn][r] + bb[fn]), s);
      s += __shfl_xor(s, 1);
      s += __shfl_xor(s, 2);
      s += __shfl_xor(s, 4);
      s += __shfl_xor(s, 8);
      if (tx == 0)
        atomicAdd(&logits[m0 + wm * 32 + fm * 16 + qd * 4 + r], s);
    }
  }
}

__global__ __launch_bounds__(256) void pool_masked_kernel(
    const float* __restrict__ feat, const float* __restrict__ w,
    float* __restrict__ pool, int S, int chunk) {
  const int b = blockIdx.x, c = blockIdx.y, tid = threadIdx.x;
  const int h0 = tid * 2;
  const int s0 = c * chunk;
  const int s1 = min(S, s0 + chunk);
  const float* fb = feat + (size_t)b * S * HDIM;
  const float* wb = w + (size_t)b * S;
  float ax = 0.0f, ay = 0.0f;
  for (int s = s0; s < s1; ++s) {
    const float ws = wb[s];
    if (ws != 0.0f) {
      const float2 f = *(const float2*)(fb + (size_t)s * HDIM + h0);
      ax = fmaf(ws, f.x, ax);
      ay = fmaf(ws, f.y, ay);
    }
  }
  atomicAdd(&pool[b * HDIM + h0], ax);
  atomicAdd(&pool[b * HDIM + h0 + 1], ay);
}

__global__ __launch_bounds__(256) void pool_seg_kernel(
    const float* __restrict__ node_h, const float* __restrict__ w,
    const int* __restrict__ seg_start, float* __restrict__ pool) {
  const int b = blockIdx.x, c = blockIdx.y, tid = threadIdx.x;
  const int h0 = tid * 2;
  const int s0 = seg_start[b], s1 = seg_start[b + 1];
  const int nseg = s1 - s0;
  const int chunk = (nseg + (int)gridDim.y - 1) / (int)gridDim.y;
  const int a0 = s0 + c * chunk;
  const int a1 = min(s1, a0 + chunk);
  float ax = 0.0f, ay = 0.0f;
  for (int s = a0; s < a1; ++s) {
    const float ws = w[s];
    const float2 f = *(const float2*)(node_h + (size_t)s * HDIM + h0);
    ax = fmaf(ws, fast_tanh(f.x), ax);
    ay = fmaf(ws, fast_tanh(f.y), ay);
  }
  atomicAdd(&pool[b * HDIM + h0], ax);
  atomicAdd(&pool[b * HDIM + h0 + 1], ay);
}

// ===========================================================================
// Shared small kernels
// ===========================================================================

__global__ void zero_kernel(float* __restrict__ p, int n) {
  const int i = blockIdx.x * 256 + threadIdx.x;
  if (i < n) p[i] = 0.0f;
}

__global__ void seg_bounds_kernel(const int* __restrict__ seg, int N,
                                  int* __restrict__ seg_start) {
  const int b = threadIdx.x;
  if (b > BATCH) return;
  int lo = 0, hi = N;
  while (lo < hi) {
    const int mid = (lo + hi) >> 1;
    if (seg[mid] < b) lo = mid + 1; else hi = mid;
  }
  seg_start[b] = lo;
}

__global__ __launch_bounds__(256) void softmax_masked_kernel(
    float* __restrict__ logits, const int* __restrict__ lens, int S) {
  __shared__ float smax[4], ssum[4];
  const int b = blockIdx.x, tid = threadIdx.x;
  const int len = lens[b];
  float* l = logits + (size_t)b * S;
  float mymax = -1e30f;
  for (int s = tid; s < len; s += 256) mymax = fmaxf(mymax, l[s]);
#pragma unroll
  for (int off = 32; off; off >>= 1) mymax = fmaxf(mymax, __shfl_xor(mymax, off));
  if ((tid & 63) == 0) smax[tid >> 6] = mymax;
  __syncthreads();
  const float bmax = fmaxf(fmaxf(smax[0], smax[1]), fmaxf(smax[2], smax[3]));
  float mysum = 0.0f;
  for (int s = tid; s < len; s += 256) mysum += __expf(l[s] - bmax);
#pragma unroll
  for (int off = 32; off; off >>= 1) mysum += __shfl_xor(mysum, off);
  if ((tid & 63) == 0) ssum[tid >> 6] = mysum;
  __syncthreads();
  const float inv = 1.0f / (ssum[0] + ssum[1] + ssum[2] + ssum[3]);
  for (int s = tid; s < S; s += 256)
    l[s] = (s < len) ? __expf(l[s] - bmax) * inv : 0.0f;
}

__global__ __launch_bounds__(256) void softmax_seg_kernel(
    float* __restrict__ logits, const int* __restrict__ seg_start) {
  __shared__ float smax[4], ssum[4];
  const int b = blockIdx.x, tid = threadIdx.x;
  const int s0 = seg_start[b], s1 = seg_start[b + 1];
  float mymax = -1e30f;
  for (int s = s0 + tid; s < s1; s += 256) mymax = fmaxf(mymax, logits[s]);
#pragma unroll
  for (int off = 32; off; off >>= 1) mymax = fmaxf(mymax, __shfl_xor(mymax, off));
  if ((tid & 63) == 0) smax[tid >> 6] = mymax;
  __syncthreads();
  const float bmax = fmaxf(fmaxf(smax[0], smax[1]), fmaxf(smax[2], smax[3]));
  float mysum = 0.0f;
  for (int s = s0 + tid; s < s1; s += 256) mysum += __expf(logits[s] - bmax);
#pragma unroll
  for (int off = 32; off; off >>= 1) mysum += __shfl_xor(mysum, off);
  if ((tid & 63) == 0) ssum[tid >> 6] = mysum;
  __syncthreads();
  const float inv = 1.0f / (ssum[0] + ssum[1] + ssum[2] + ssum[3]);
  for (int s = s0 + tid; s < s1; s += 256)
    logits[s] = __expf(logits[s] - bmax) * inv;
}

__global__ __launch_bounds__(256) void code_feat_kernel(
    const float* __restrict__ tok_pool, const float* __restrict__ ast_pool,
    const float* __restrict__ Wf, const float* __restrict__ bfv,
    float* __restrict__ code) {
  __shared__ float cat[2 * HDIM];
  const int b = blockIdx.x, tid = threadIdx.x;
  for (int i = tid; i < HDIM; i += 256) {
    cat[i] = fast_tanh(tok_pool[(size_t)b * HDIM + i]);
    cat[HDIM + i] = fast_tanh(ast_pool[(size_t)b * HDIM + i]);
  }
  __syncthreads();
  float acc0 = bfv[tid], acc1 = bfv[tid + 256];
  for (int k = 0; k < 2 * HDIM; ++k) {
    const float ck = cat[k];
    acc0 = fmaf(ck, Wf[(size_t)k * HDIM + tid], acc0);
    acc1 = fmaf(ck, Wf[(size_t)k * HDIM + tid + 256], acc1);
  }
  code[(size_t)b * HDIM + tid] = fast_tanh(acc0);
  code[(size_t)b * HDIM + tid + 256] = fast_tanh(acc1);
}

__global__ __launch_bounds__(256) void sims_kernel(
    const float* __restrict__ code, const float* __restrict__ da_pool,
    const float* __restrict__ dn_pool, float* __restrict__ terms) {
  __shared__ float sr[4][5];
  const int b = blockIdx.x, tid = threadIdx.x;
  float c2 = 0, a2 = 0, n2 = 0, ca = 0, cn = 0;
  for (int i = tid; i < HDIM; i += 256) {
    const float cf = code[(size_t)b * HDIM + i];
    const float av = fast_tanh(fast_tanh(da_pool[(size_t)b * HDIM + i]));
    const float nv = fast_tanh(fast_tanh(dn_pool[(size_t)b * HDIM + i]));
    c2 = fmaf(cf, cf, c2); a2 = fmaf(av, av, a2); n2 = fmaf(nv, nv, n2);
    ca = fmaf(cf, av, ca); cn = fmaf(cf, nv, cn);
  }
#pragma unroll
  for (int off = 32; off; off >>= 1) {
    c2 += __shfl_xor(c2, off); a2 += __shfl_xor(a2, off); n2 += __shfl_xor(n2, off);
    ca += __shfl_xor(ca, off); cn += __shfl_xor(cn, off);
  }
  const int wv = tid >> 6;
  if ((tid & 63) == 0) {
    sr[wv][0] = c2; sr[wv][1] = a2; sr[wv][2] = n2; sr[wv][3] = ca; sr[wv][4] = cn;
  }
  __syncthreads();
  if (tid == 0) {
    c2 = sr[0][0] + sr[1][0] + sr[2][0] + sr[3][0];
    a2 = sr[0][1] + sr[1][1] + sr[2][1] + sr[3][1];
    n2 = sr[0][2] + sr[1][2] + sr[2][2] + sr[3][2];
    ca = sr[0][3] + sr[1][3] + sr[2][3] + sr[3][3];
    cn = sr[0][4] + sr[1][4] + sr[2][4] + sr[3][4];
    const float nc = fmaxf(sqrtf(c2), 1e-8f);
    const float na = fmaxf(sqrtf(a2), 1e-8f);
    const float nn = fmaxf(sqrtf(n2), 1e-8f);
    const float as = ca / (nc * na);
    const float ns = cn / (nc * nn);
    terms[b] = fmaxf(0.05f - as + ns, 1e-6f);
  }
}

__global__ void loss_kernel(const float* __restrict__ terms, float* __restrict__ out) {
  const int tid = threadIdx.x;  // 128
  float v = terms[tid];
#pragma unroll
  for (int off = 32; off; off >>= 1) v += __shfl_xor(v, off);
  __shared__ float sr[2];
  if ((tid & 63) == 0) sr[tid >> 6] = v;
  __syncthreads();
  if (tid == 0) out[0] = (sr[0] + sr[1]) * (1.0f / (float)BATCH);
}

// ===========================================================================

extern "C" void kernel_launch(void* const* d_in, const int* in_sizes, int n_in,
                              void* d_out, int out_size, void* d_ws, size_t ws_size,
                              hipStream_t stream) {
  (void)in_sizes; (void)n_in; (void)out_size;
  const float* token_feat = (const float*)d_in[0];
  const int*   token_len  = (const int*)d_in[1];
  const float* node_h     = (const float*)d_in[2];
  const int*   seg_ids    = (const int*)d_in[3];
  const float* da_feat    = (const float*)d_in[4];
  const int*   da_len     = (const int*)d_in[5];
  const float* dn_feat    = (const float*)d_in[6];
  const int*   dn_len     = (const int*)d_in[7];
  const float* Wt = (const float*)d_in[8];
  const float* bt = (const float*)d_in[9];
  const float* vt = (const float*)d_in[10];
  const float* Wa = (const float*)d_in[12];
  const float* ba = (const float*)d_in[13];
  const float* va = (const float*)d_in[14];
  const float* Wd = (const float*)d_in[16];
  const float* bd = (const float*)d_in[17];
  const float* vd = (const float*)d_in[18];
  const float* Wf  = (const float*)d_in[20];
  const float* bfv = (const float*)d_in[21];

  const int MTOK = 128 * 512;   // 65536
  const int MDESC = 128 * 128;  // 16384
  const int NNODES = 65536;

  float* ws = (float*)d_ws;
  float* logits_tok  = ws;
  float* logits_node = logits_tok + MTOK;
  float* logits_da   = logits_node + NNODES;
  float* logits_dn   = logits_da + MDESC;
  float* tok_pool    = logits_dn + MDESC;
  float* ast_pool    = tok_pool + 128 * HDIM;
  float* da_pool     = ast_pool + 128 * HDIM;
  float* dn_pool     = da_pool + 128 * HDIM;
  float* code        = dn_pool + 128 * HDIM;
  float* terms       = code + 128 * HDIM;
  int*   seg_start   = (int*)(terms + 128);
  _Float16* hbase = (_Float16*)(seg_start + 256);
  _Float16* W2t = hbase;                      // 512*512
  _Float16* W2a = W2t + HDIM * HDIM;
  _Float16* W2d = W2a + HDIM * HDIM;
  _Float16* A2tok  = W2d + HDIM * HDIM;       // 8*65536*64
  _Float16* A2node = A2tok + (size_t)8 * MTOK * 64;
  _Float16* A2da   = A2node + (size_t)8 * NNODES * 64;
  _Float16* A2dn   = A2da + (size_t)8 * MDESC * 64;
  const size_t NEED = (size_t)((char*)(A2dn + (size_t)8 * MDESC * 64) - (char*)d_ws);

  const int ZTOT = MTOK + NNODES + 2 * MDESC + 5 * 128 * HDIM;  // logits + pools + code slot safety
  zero_kernel<<<dim3((ZTOT + 255) / 256), 256, 0, stream>>>(ws, ZTOT);
  seg_bounds_kernel<<<1, 256, 0, stream>>>(seg_ids, NNODES, seg_start);

  if (ws_size >= NEED) {
    // ---- fast path: pre-convert everything to tiled swizzled f16 ----
    cvt_w_kernel<<<128, 256, 0, stream>>>(Wt, W2t);
    cvt_w_kernel<<<128, 256, 0, stream>>>(Wa, W2a);
    cvt_w_kernel<<<128, 256, 0, stream>>>(Wd, W2d);
    cvt_tile_kernel<false><<<2048, 256, 0, stream>>>(token_feat, A2tok, MTOK);
    cvt_tile_kernel<true ><<<2048, 256, 0, stream>>>(node_h, A2node, NNODES);
    cvt_tile_kernel<false><<<2048, 256, 0, stream>>>(da_feat, A2da, MDESC);
    cvt_tile_kernel<false><<<2048, 256, 0, stream>>>(dn_feat, A2dn, MDESC);

    gemm_logits_f16_kernel<<<MTOK / 128 * 2, 512, 0, stream>>>(A2tok, W2t, bt, vt, logits_tok, MTOK);
    gemm_logits_f16_kernel<<<NNODES / 128 * 2, 512, 0, stream>>>(A2node, W2a, ba, va, logits_node, NNODES);
    gemm_logits_f16_kernel<<<MDESC / 128 * 2, 512, 0, stream>>>(A2da, W2d, bd, vd, logits_da, MDESC);
    gemm_logits_f16_kernel<<<MDESC / 128 * 2, 512, 0, stream>>>(A2dn, W2d, bd, vd, logits_dn, MDESC);

    softmax_masked_kernel<<<BATCH, 256, 0, stream>>>(logits_tok, token_len, 512);
    softmax_masked_kernel<<<BATCH, 256, 0, stream>>>(logits_da, da_len, 128);
    softmax_masked_kernel<<<BATCH, 256, 0, stream>>>(logits_dn, dn_len, 128);
    softmax_seg_kernel<<<BATCH, 256, 0, stream>>>(logits_node, seg_start);

    pool_tiled_masked_kernel<<<dim3(BATCH, 8), 256, 0, stream>>>(A2tok, logits_tok, tok_pool, MTOK, 512, 64);
    pool_tiled_masked_kernel<<<dim3(BATCH, 2), 256, 0, stream>>>(A2da, logits_da, da_pool, MDESC, 128, 64);
    pool_tiled_masked_kernel<<<dim3(BATCH, 2), 256, 0, stream>>>(A2dn, logits_dn, dn_pool, MDESC, 128, 64);
    pool_tiled_seg_kernel<<<dim3(BATCH, 4), 256, 0, stream>>>(A2node, logits_node, seg_start, ast_pool, NNODES);
  } else {
    // ---- fallback: R2 path (reg-staged GEMM, fp32 pools) ----
    _Float16* Wt_t = hbase;
    _Float16* Wa_t = Wt_t + HDIM * HDIM;
    _Float16* Wd_t = Wa_t + HDIM * HDIM;
    transpose_w_kernel<<<dim3(8, 8), 256, 0, stream>>>(Wt, Wt_t);
    transpose_w_kernel<<<dim3(8, 8), 256, 0, stream>>>(Wa, Wa_t);
    transpose_w_kernel<<<dim3(8, 8), 256, 0, stream>>>(Wd, Wd_t);

    gemm_logits_mfma_kernel<false><<<MTOK / 128 * 2, 512, 0, stream>>>(token_feat, Wt_t, bt, vt, logits_tok);
    gemm_logits_mfma_kernel<true ><<<NNODES / 128 * 2, 512, 0, stream>>>(node_h, Wa_t, ba, va, logits_node);
    gemm_logits_mfma_kernel<false><<<MDESC / 128 * 2, 512, 0, stream>>>(da_feat, Wd_t, bd, vd, logits_da);
    gemm_logits_mfma_kernel<false><<<MDESC / 128 * 2, 512, 0, stream>>>(dn_feat, Wd_t, bd, vd, logits_dn);

    softmax_masked_kernel<<<BATCH, 256, 0, stream>>>(logits_tok, token_len, 512);
    softmax_masked_kernel<<<BATCH, 256, 0, stream>>>(logits_da, da_len, 128);
    softmax_masked_kernel<<<BATCH, 256, 0, stream>>>(logits_dn, dn_len, 128);
    softmax_seg_kernel<<<BATCH, 256, 0, stream>>>(logits_node, seg_start);

    pool_masked_kernel<<<dim3(BATCH, 8), 256, 0, stream>>>(token_feat, logits_tok, tok_pool, 512, 64);
    pool_masked_kernel<<<dim3(BATCH, 2), 256, 0, stream>>>(da_feat, logits_da, da_pool, 128, 64);
    pool_masked_kernel<<<dim3(BATCH, 2), 256, 0, stream>>>(dn_feat, logits_dn, dn_pool, 128, 64);
    pool_seg_kernel<<<dim3(BATCH, 4), 256, 0, stream>>>(node_h, logits_node, seg_start, ast_pool);
  }

  code_feat_kernel<<<BATCH, 256, 0, stream>>>(tok_pool, ast_pool, Wf, bfv, code);
  sims_kernel<<<BATCH, 256, 0, stream>>>(code, da_pool, dn_pool, terms);
  loss_kernel<<<1, 128, 0, stream>>>(terms, (float*)d_out);
}

// Round 4
// 388.698 us; speedup vs baseline: 3.8001x; 1.2080x over previous
//
#include <hip/hip_runtime.h>
#include <math.h>

#define HDIM 512
#define BATCH 128

typedef _Float16 f16x8 __attribute__((ext_vector_type(8)));
typedef float f32x4 __attribute__((ext_vector_type(4)));

__device__ __forceinline__ float fast_tanh(float x) {
  float e = __expf(2.0f * x);
  return 1.0f - 2.0f / (e + 1.0f);
}

__device__ __forceinline__ void gload_lds16(const void* g, void* l) {
  __builtin_amdgcn_global_load_lds(
      (const __attribute__((address_space(1))) unsigned int*)g,
      (__attribute__((address_space(3))) unsigned int*)l, 16, 0, 0);
}

// ---------------------------------------------------------------------------
// A [Mrows][512] fp32 -> A2 rows [m_off..m_off+Mrows) of [8 kt][Mtot][64] f16,
// XOR-swizzled per row (byte ^= (row&7)<<4) so linear global_load_lds staging
// + swizzled ds_read_b128 is bank-conflict-free (G21 both-sides rule).
// ---------------------------------------------------------------------------
template <bool TANH>
__global__ __launch_bounds__(256) void cvt_tile_kernel(
    const float* __restrict__ A, _Float16* __restrict__ A2,
    int Mtot, int m_off, int Mrows) {
  const int total = Mrows * 64;  // 16B chunks
  for (int i = blockIdx.x * 256 + threadIdx.x; i < total; i += gridDim.x * 256) {
    const int m = i >> 6, c = i & 63;
    const int kt = c >> 3, cc = c & 7;
    const float* src = A + (size_t)m * HDIM + c * 8;
    const float4 x = ((const float4*)src)[0];
    const float4 y = ((const float4*)src)[1];
    f16x8 h;
    if (TANH) {
      h[0] = (_Float16)fast_tanh(x.x); h[1] = (_Float16)fast_tanh(x.y);
      h[2] = (_Float16)fast_tanh(x.z); h[3] = (_Float16)fast_tanh(x.w);
      h[4] = (_Float16)fast_tanh(y.x); h[5] = (_Float16)fast_tanh(y.y);
      h[6] = (_Float16)fast_tanh(y.z); h[7] = (_Float16)fast_tanh(y.w);
    } else {
      h[0] = (_Float16)x.x; h[1] = (_Float16)x.y;
      h[2] = (_Float16)x.z; h[3] = (_Float16)x.w;
      h[4] = (_Float16)y.x; h[5] = (_Float16)y.y;
      h[6] = (_Float16)y.z; h[7] = (_Float16)y.w;
    }
    const int dr = m_off + m;
    char* dst = (char*)A2 + ((size_t)kt * Mtot + dr) * 128 + ((cc * 16) ^ ((dr & 7) << 4));
    *(f16x8*)dst = h;
  }
}

// W [512 k][512 n] fp32 -> W2 [8 kt][512 n][64 k] f16, XOR-swizzled by n.
// grid (128, 3): y selects which of the three weight matrices.
__global__ __launch_bounds__(256) void cvt_w3_kernel(
    const float* __restrict__ Wt, const float* __restrict__ Wa,
    const float* __restrict__ Wd, _Float16* __restrict__ W2t,
    _Float16* __restrict__ W2a, _Float16* __restrict__ W2d) {
  const int i = blockIdx.x * 256 + threadIdx.x;  // 512*64
  if (i >= 512 * 64) return;
  const float* W = (blockIdx.y == 0) ? Wt : (blockIdx.y == 1) ? Wa : Wd;
  _Float16* W2 = (blockIdx.y == 0) ? W2t : (blockIdx.y == 1) ? W2a : W2d;
  const int n = i & 511, g = i >> 9;
  const int kt = g >> 3, cc = g & 7;
  f16x8 h;
#pragma unroll
  for (int j = 0; j < 8; ++j)
    h[j] = (_Float16)W[(size_t)(kt * 64 + cc * 8 + j) * HDIM + n];
  char* dst = (char*)W2 + ((size_t)kt * 512 + n) * 128 + ((cc * 16) ^ ((n & 7) << 4));
  *(f16x8*)dst = h;
}

// ---------------------------------------------------------------------------
// Fused logit GEMM, double-buffered 2-phase (T3-min recipe):
//   logits[m] += sum_n v[n] * tanh( (A@W)[m,n] + bias[n] )
// A2: [8][M][64] swizzled f16; W2: [8][512][64] swizzled f16.
// Block 128x128, BK=64, 256 thr = 4 waves (2M x 2N), wave tile 64x64.
// STAGE(next buf) issued BEFORE compute(cur); one __syncthreads per K-step
// (its vmcnt(0) drain lands after the compute phase hid the load latency).
// ---------------------------------------------------------------------------
__global__ __launch_bounds__(256) void gemm_logits_dbuf_kernel(
    const _Float16* __restrict__ A2, const _Float16* __restrict__ W2,
    const float* __restrict__ bias, const float* __restrict__ vvec,
    float* __restrict__ logits, int M) {
  __shared__ __align__(16) _Float16 As[2][128 * 64];  // 2 x 16 KB
  __shared__ __align__(16) _Float16 Bs[2][128 * 64];  // 2 x 16 KB

  const int tid = threadIdx.x;
  const int nwg = gridDim.x;
  const int qq = nwg >> 3;
  const int raw = blockIdx.x;
  const int swz = (raw & 7) * qq + (raw >> 3);  // XCD-bijective (nwg%8==0)
  const int nb = swz & 3;
  const int mb = swz >> 2;
  const size_t m0 = (size_t)mb * 128;
  const int n0 = nb * 128;

  const int lane = tid & 63, wid = tid >> 6;
  const int tx = lane & 15, qd = lane >> 4;
  const int wm = wid >> 1, wn = wid & 1;

  const char* gA = (const char*)A2 + m0 * 128;
  const char* gB = (const char*)W2 + (size_t)n0 * 128;
  const size_t sA = (size_t)M * 128;
  const size_t sB = (size_t)512 * 128;
  const int lo = tid * 16;

  f32x4 acc[4][4];
#pragma unroll
  for (int i = 0; i < 4; ++i)
#pragma unroll
    for (int j = 0; j < 4; ++j) acc[i][j] = (f32x4){0.f, 0.f, 0.f, 0.f};

  auto STAGE = [&](int buf, int kt) {
    const char* a = gA + (size_t)kt * sA;
    const char* b = gB + (size_t)kt * sB;
#pragma unroll
    for (int p = 0; p < 4; ++p) {
      gload_lds16(a + lo + p * 4096, (char*)As[buf] + lo + p * 4096);
      gload_lds16(b + lo + p * 4096, (char*)Bs[buf] + lo + p * 4096);
    }
  };

  auto COMPUTE = [&](int buf) {
#pragma unroll
    for (int ks = 0; ks < 2; ++ks) {
      f16x8 aF[4], bF[4];
#pragma unroll
      for (int f = 0; f < 4; ++f) {
        const int row = wm * 64 + f * 16 + tx;
        int byA = row * 128 + (ks * 32 + qd * 8) * 2;
        byA ^= (row & 7) << 4;
        aF[f] = *(const f16x8*)((const char*)As[buf] + byA);
        const int n = wn * 64 + f * 16 + tx;
        int byB = n * 128 + (ks * 32 + qd * 8) * 2;
        byB ^= (n & 7) << 4;
        bF[f] = *(const f16x8*)((const char*)Bs[buf] + byB);
      }
#pragma unroll
      for (int i = 0; i < 4; ++i)
#pragma unroll
        for (int j = 0; j < 4; ++j)
          acc[i][j] = __builtin_amdgcn_mfma_f32_16x16x32_f16(aF[i], bF[j], acc[i][j], 0, 0, 0);
    }
  };

  STAGE(0, 0);
  __syncthreads();
#pragma unroll
  for (int kt = 0; kt < 8; ++kt) {
    const int cur = kt & 1;
    if (kt < 7) STAGE(cur ^ 1, kt + 1);
    COMPUTE(cur);
    __syncthreads();
  }

  // epilogue: t = tanh(acc + bias[n]) * v[n], reduce over this block's 128 n's
  float vv[4], bb[4];
#pragma unroll
  for (int j = 0; j < 4; ++j) {
    const int n = n0 + wn * 64 + j * 16 + tx;
    vv[j] = vvec[n];
    bb[j] = bias[n];
  }
#pragma unroll
  for (int i = 0; i < 4; ++i) {
#pragma unroll
    for (int r = 0; r < 4; ++r) {
      float s = 0.0f;
#pragma unroll
      for (int j = 0; j < 4; ++j)
        s = fmaf(vv[j], fast_tanh(acc[i][j][r] + bb[j]), s);
      s += __shfl_xor(s, 1);
      s += __shfl_xor(s, 2);
      s += __shfl_xor(s, 4);
      s += __shfl_xor(s, 8);
      if (tx == 0)
        atomicAdd(&logits[m0 + wm * 64 + i * 16 + qd * 4 + r], s);
    }
  }
}

// ---------------------------------------------------------------------------
// small/streaming kernels
// ---------------------------------------------------------------------------

__global__ void zero_kernel(float* __restrict__ p, int n) {
  const int i = blockIdx.x * 256 + threadIdx.x;
  if (i < n) p[i] = 0.0f;
}

__global__ void seg_bounds_kernel(const int* __restrict__ seg, int N,
                                  int* __restrict__ seg_start) {
  const int b = threadIdx.x;
  if (b > BATCH) return;
  int lo = 0, hi = N;
  while (lo < hi) {
    const int mid = (lo + hi) >> 1;
    if (seg[mid] < b) lo = mid + 1; else hi = mid;
  }
  seg_start[b] = lo;
}

// grid (128, 4): y=0 token (S=512), y=1 desc-anchor, y=2 desc-neg, y=3 node-seg
__global__ __launch_bounds__(256) void softmax_all_kernel(
    float* __restrict__ ltok, float* __restrict__ ldesc,
    float* __restrict__ lnode, const int* __restrict__ tlen,
    const int* __restrict__ dalen, const int* __restrict__ dnlen,
    const int* __restrict__ seg_start) {
  __shared__ float smax[4], ssum[4];
  const int b = blockIdx.x, mode = blockIdx.y, tid = threadIdx.x;
  float* l;
  int s0, s1, fill_end;
  if (mode == 0)      { l = ltok + (size_t)b * 512;          s0 = 0; s1 = tlen[b];  fill_end = 512; }
  else if (mode == 1) { l = ldesc + (size_t)b * 128;         s0 = 0; s1 = dalen[b]; fill_end = 128; }
  else if (mode == 2) { l = ldesc + 16384 + (size_t)b * 128; s0 = 0; s1 = dnlen[b]; fill_end = 128; }
  else                { l = lnode; s0 = seg_start[b]; s1 = seg_start[b + 1]; fill_end = -1; }

  float mymax = -1e30f;
  for (int s = s0 + tid; s < s1; s += 256) mymax = fmaxf(mymax, l[s]);
#pragma unroll
  for (int off = 32; off; off >>= 1) mymax = fmaxf(mymax, __shfl_xor(mymax, off));
  if ((tid & 63) == 0) smax[tid >> 6] = mymax;
  __syncthreads();
  const float bmax = fmaxf(fmaxf(smax[0], smax[1]), fmaxf(smax[2], smax[3]));
  float mysum = 0.0f;
  for (int s = s0 + tid; s < s1; s += 256) mysum += __expf(l[s] - bmax);
#pragma unroll
  for (int off = 32; off; off >>= 1) mysum += __shfl_xor(mysum, off);
  if ((tid & 63) == 0) ssum[tid >> 6] = mysum;
  __syncthreads();
  const float inv = 1.0f / (ssum[0] + ssum[1] + ssum[2] + ssum[3]);
  for (int s = s0 + tid; s < s1; s += 256) l[s] = __expf(l[s] - bmax) * inv;
  if (fill_end > 0)
    for (int s = s1 + tid; s < fill_end; s += 256) l[s] = 0.0f;
}

// grid (128, 12): c<8 token chunks, c in {8,9} desc-anchor, {10,11} desc-neg
__global__ __launch_bounds__(256) void pool_masked_all_kernel(
    const _Float16* __restrict__ A2tok, const _Float16* __restrict__ A2desc,
    const float* __restrict__ ltok, const float* __restrict__ ldesc,
    float* __restrict__ tok_pool, float* __restrict__ da_pool,
    float* __restrict__ dn_pool) {
  const int b = blockIdx.x, c = blockIdx.y, tid = threadIdx.x;
  const _Float16* A2;
  const float* w;
  float* out;
  int Mtot, rbase, s0;
  if (c < 8)       { A2 = A2tok;  Mtot = 65536; rbase = b * 512;         w = ltok;  out = tok_pool; s0 = c * 64; }
  else if (c < 10) { A2 = A2desc; Mtot = 32768; rbase = b * 128;         w = ldesc; out = da_pool;  s0 = (c - 8) * 64; }
  else             { A2 = A2desc; Mtot = 32768; rbase = 16384 + b * 128; w = ldesc; out = dn_pool;  s0 = (c - 10) * 64; }
  const int h = tid * 2;
  const int kt = h >> 6, col = h & 63;
  const char* base = (const char*)A2 + (size_t)kt * Mtot * 128;
  float ax = 0.0f, ay = 0.0f;
  for (int s = s0; s < s0 + 64; ++s) {
    const int row = rbase + s;
    const float wsc = w[row];
    if (wsc != 0.0f) {
      const unsigned u = *(const unsigned*)(base + (size_t)row * 128 + ((col * 2) ^ ((row & 7) << 4)));
      const _Float16* hp = (const _Float16*)&u;
      ax = fmaf(wsc, (float)hp[0], ax);
      ay = fmaf(wsc, (float)hp[1], ay);
    }
  }
  atomicAdd(&out[b * HDIM + h], ax);
  atomicAdd(&out[b * HDIM + h + 1], ay);
}

// ast_pool[b,h] += sum_{n in seg b} w[n] * A2node[n,h] (tanh pre-applied)
__global__ __launch_bounds__(256) void pool_tiled_seg_kernel(
    const _Float16* __restrict__ A2, const float* __restrict__ w,
    const int* __restrict__ seg_start, float* __restrict__ pool, int Mtot) {
  const int b = blockIdx.x, c = blockIdx.y, tid = threadIdx.x;
  const int h = tid * 2;
  const int kt = h >> 6, col = h & 63;
  const char* base = (const char*)A2 + (size_t)kt * Mtot * 128;
  const int s0 = seg_start[b], s1 = seg_start[b + 1];
  const int nseg = s1 - s0;
  const int chunk = (nseg + (int)gridDim.y - 1) / (int)gridDim.y;
  const int a0 = s0 + c * chunk;
  const int a1 = min(s1, a0 + chunk);
  float ax = 0.0f, ay = 0.0f;
  for (int s = a0; s < a1; ++s) {
    const float wsc = w[s];
    const unsigned u = *(const unsigned*)(base + (size_t)s * 128 + ((col * 2) ^ ((s & 7) << 4)));
    const _Float16* hp = (const _Float16*)&u;
    ax = fmaf(wsc, (float)hp[0], ax);
    ay = fmaf(wsc, (float)hp[1], ay);
  }
  atomicAdd(&pool[b * HDIM + h], ax);
  atomicAdd(&pool[b * HDIM + h + 1], ay);
}

// code-pre GEMM: parts[kb][b][n-chunk] = cat[b][k-chunk] @ Wf[k-chunk][n-chunk]
// cat[b][k] = tanh(tok_pool|ast_pool). grid (4 nb, 16 kb), 256 thr, fp32 VALU.
__global__ __launch_bounds__(256) void code_gemm_kernel(
    const float* __restrict__ tok_pool, const float* __restrict__ ast_pool,
    const float* __restrict__ Wf, float* __restrict__ parts) {
  __shared__ float catS[128][65];
  __shared__ float4 wfS[64][32];
  const int nb = blockIdx.x, kb = blockIdx.y, tid = threadIdx.x;
  const int k0 = kb * 64;
  const float* src = (k0 < 512) ? (tok_pool + k0) : (ast_pool + (k0 - 512));
  for (int i = tid; i < 128 * 16; i += 256) {
    const int r = i >> 4, c4 = i & 15;
    const float4 v = *(const float4*)(src + (size_t)r * HDIM + c4 * 4);
    catS[r][c4 * 4 + 0] = fast_tanh(v.x);
    catS[r][c4 * 4 + 1] = fast_tanh(v.y);
    catS[r][c4 * 4 + 2] = fast_tanh(v.z);
    catS[r][c4 * 4 + 3] = fast_tanh(v.w);
  }
  for (int i = tid; i < 64 * 32; i += 256) {
    const int r = i >> 5, c = i & 31;
    wfS[r][c] = *(const float4*)(Wf + (size_t)(k0 + r) * HDIM + nb * 128 + c * 4);
  }
  __syncthreads();
  const int tb = tid >> 4, tn = tid & 15;
  const int b0 = tb * 8, n0l = tn * 8;
  float acc[8][8];
#pragma unroll
  for (int i = 0; i < 8; ++i)
#pragma unroll
    for (int j = 0; j < 8; ++j) acc[i][j] = 0.0f;
  for (int k = 0; k < 64; ++k) {
    float a[8];
#pragma unroll
    for (int i = 0; i < 8; ++i) a[i] = catS[b0 + i][k];
    const float4 w0 = wfS[k][tn * 2], w1 = wfS[k][tn * 2 + 1];
    const float wv[8] = {w0.x, w0.y, w0.z, w0.w, w1.x, w1.y, w1.z, w1.w};
#pragma unroll
    for (int i = 0; i < 8; ++i)
#pragma unroll
      for (int j = 0; j < 8; ++j) acc[i][j] = fmaf(a[i], wv[j], acc[i][j]);
  }
  float* dst = parts + ((size_t)kb * 128) * HDIM + nb * 128;
#pragma unroll
  for (int i = 0; i < 8; ++i) {
    const float4 o0 = {acc[i][0], acc[i][1], acc[i][2], acc[i][3]};
    const float4 o1 = {acc[i][4], acc[i][5], acc[i][6], acc[i][7]};
    *(float4*)(dst + (size_t)(b0 + i) * HDIM + n0l) = o0;
    *(float4*)(dst + (size_t)(b0 + i) * HDIM + n0l + 4) = o1;
  }
}

// per-sample hinge terms; folds code = tanh(sum_kb parts + bf). grid 128.
__global__ __launch_bounds__(256) void sims_kernel(
    const float* __restrict__ parts, const float* __restrict__ bfv,
    const float* __restrict__ da_pool, const float* __restrict__ dn_pool,
    float* __restrict__ terms) {
  __shared__ float sr[4][5];
  const int b = blockIdx.x, tid = threadIdx.x;
  float c2 = 0, a2 = 0, n2 = 0, ca = 0, cn = 0;
  for (int i = tid; i < HDIM; i += 256) {
    float pre = bfv[i];
#pragma unroll
    for (int kb = 0; kb < 16; ++kb)
      pre += parts[((size_t)kb * 128 + b) * HDIM + i];
    const float cf = fast_tanh(pre);
    const float av = fast_tanh(fast_tanh(da_pool[(size_t)b * HDIM + i]));
    const float nv = fast_tanh(fast_tanh(dn_pool[(size_t)b * HDIM + i]));
    c2 = fmaf(cf, cf, c2); a2 = fmaf(av, av, a2); n2 = fmaf(nv, nv, n2);
    ca = fmaf(cf, av, ca); cn = fmaf(cf, nv, cn);
  }
#pragma unroll
  for (int off = 32; off; off >>= 1) {
    c2 += __shfl_xor(c2, off); a2 += __shfl_xor(a2, off); n2 += __shfl_xor(n2, off);
    ca += __shfl_xor(ca, off); cn += __shfl_xor(cn, off);
  }
  const int wv = tid >> 6;
  if ((tid & 63) == 0) {
    sr[wv][0] = c2; sr[wv][1] = a2; sr[wv][2] = n2; sr[wv][3] = ca; sr[wv][4] = cn;
  }
  __syncthreads();
  if (tid == 0) {
    c2 = sr[0][0] + sr[1][0] + sr[2][0] + sr[3][0];
    a2 = sr[0][1] + sr[1][1] + sr[2][1] + sr[3][1];
    n2 = sr[0][2] + sr[1][2] + sr[2][2] + sr[3][2];
    ca = sr[0][3] + sr[1][3] + sr[2][3] + sr[3][3];
    cn = sr[0][4] + sr[1][4] + sr[2][4] + sr[3][4];
    const float nc = fmaxf(sqrtf(c2), 1e-8f);
    const float na = fmaxf(sqrtf(a2), 1e-8f);
    const float nn = fmaxf(sqrtf(n2), 1e-8f);
    terms[b] = fmaxf(0.05f - ca / (nc * na) + cn / (nc * nn), 1e-6f);
  }
}

__global__ void loss_kernel(const float* __restrict__ terms, float* __restrict__ out) {
  const int tid = threadIdx.x;  // 128
  float v = terms[tid];
#pragma unroll
  for (int off = 32; off; off >>= 1) v += __shfl_xor(v, off);
  __shared__ float sr[2];
  if ((tid & 63) == 0) sr[tid >> 6] = v;
  __syncthreads();
  if (tid == 0) out[0] = (sr[0] + sr[1]) * (1.0f / (float)BATCH);
}

// ===========================================================================

extern "C" void kernel_launch(void* const* d_in, const int* in_sizes, int n_in,
                              void* d_out, int out_size, void* d_ws, size_t ws_size,
                              hipStream_t stream) {
  (void)in_sizes; (void)n_in; (void)out_size; (void)ws_size;
  const float* token_feat = (const float*)d_in[0];
  const int*   token_len  = (const int*)d_in[1];
  const float* node_h     = (const float*)d_in[2];
  const int*   seg_ids    = (const int*)d_in[3];
  const float* da_feat    = (const float*)d_in[4];
  const int*   da_len     = (const int*)d_in[5];
  const float* dn_feat    = (const float*)d_in[6];
  const int*   dn_len     = (const int*)d_in[7];
  const float* Wt = (const float*)d_in[8];
  const float* bt = (const float*)d_in[9];
  const float* vt = (const float*)d_in[10];
  const float* Wa = (const float*)d_in[12];
  const float* ba = (const float*)d_in[13];
  const float* va = (const float*)d_in[14];
  const float* Wd = (const float*)d_in[16];
  const float* bd = (const float*)d_in[17];
  const float* vd = (const float*)d_in[18];
  const float* Wf  = (const float*)d_in[20];
  const float* bfv = (const float*)d_in[21];

  const int MTOK = 65536;   // 128*512
  const int MDESC2 = 32768; // 2*128*128 (anchor ++ neg)
  const int NNODES = 65536;

  float* ws = (float*)d_ws;
  float* logits_tok  = ws;                       // 65536
  float* logits_node = logits_tok + MTOK;        // 65536
  float* logits_desc = logits_node + NNODES;     // 32768 (da ++ dn)
  float* tok_pool    = logits_desc + MDESC2;     // 65536
  float* ast_pool    = tok_pool + 128 * HDIM;
  float* da_pool     = ast_pool + 128 * HDIM;
  float* dn_pool     = da_pool + 128 * HDIM;
  float* terms       = dn_pool + 128 * HDIM;     // 128
  int*   seg_start   = (int*)(terms + 128);      // 256 slot
  float* parts       = (float*)(seg_start + 256);  // 16*128*512 = 1048576
  _Float16* W2t = (_Float16*)(parts + 16 * 128 * HDIM);
  _Float16* W2a = W2t + HDIM * HDIM;
  _Float16* W2d = W2a + HDIM * HDIM;
  _Float16* A2tok  = W2d + HDIM * HDIM;              // 8*65536*64 f16
  _Float16* A2node = A2tok + (size_t)8 * MTOK * 64;
  _Float16* A2desc = A2node + (size_t)8 * NNODES * 64;  // 8*32768*64 f16

  // zero atomically-accumulated buffers: logits + 4 pools
  const int ZTOT = MTOK + NNODES + MDESC2 + 4 * 128 * HDIM;
  zero_kernel<<<dim3((ZTOT + 255) / 256), 256, 0, stream>>>(ws, ZTOT);
  seg_bounds_kernel<<<1, 256, 0, stream>>>(seg_ids, NNODES, seg_start);

  // convert weights + activations to tiled swizzled f16
  cvt_w3_kernel<<<dim3(128, 3), 256, 0, stream>>>(Wt, Wa, Wd, W2t, W2a, W2d);
  cvt_tile_kernel<false><<<2048, 256, 0, stream>>>(token_feat, A2tok, MTOK, 0, MTOK);
  cvt_tile_kernel<true ><<<2048, 256, 0, stream>>>(node_h, A2node, NNODES, 0, NNODES);
  cvt_tile_kernel<false><<<1024, 256, 0, stream>>>(da_feat, A2desc, MDESC2, 0, 16384);
  cvt_tile_kernel<false><<<1024, 256, 0, stream>>>(dn_feat, A2desc, MDESC2, 16384, 16384);

  // fused logit GEMMs (the +c constants are softmax-invariant, skipped)
  gemm_logits_dbuf_kernel<<<MTOK / 128 * 4, 256, 0, stream>>>(A2tok, W2t, bt, vt, logits_tok, MTOK);
  gemm_logits_dbuf_kernel<<<NNODES / 128 * 4, 256, 0, stream>>>(A2node, W2a, ba, va, logits_node, NNODES);
  gemm_logits_dbuf_kernel<<<MDESC2 / 128 * 4, 256, 0, stream>>>(A2desc, W2d, bd, vd, logits_desc, MDESC2);

  softmax_all_kernel<<<dim3(BATCH, 4), 256, 0, stream>>>(
      logits_tok, logits_desc, logits_node, token_len, da_len, dn_len, seg_start);

  pool_masked_all_kernel<<<dim3(BATCH, 12), 256, 0, stream>>>(
      A2tok, A2desc, logits_tok, logits_desc, tok_pool, da_pool, dn_pool);
  pool_tiled_seg_kernel<<<dim3(BATCH, 4), 256, 0, stream>>>(
      A2node, logits_node, seg_start, ast_pool, NNODES);

  code_gemm_kernel<<<dim3(4, 16), 256, 0, stream>>>(tok_pool, ast_pool, Wf, parts);
  sims_kernel<<<BATCH, 256, 0, stream>>>(parts, bfv, da_pool, dn_pool, terms);
  loss_kernel<<<1, 128, 0, stream>>>(terms, (float*)d_out);
}

// Round 5
// 374.358 us; speedup vs baseline: 3.9457x; 1.0383x over previous
//
#include <hip/hip_runtime.h>
#include <math.h>

#define HDIM 512
#define BATCH 128

typedef _Float16 f16x8 __attribute__((ext_vector_type(8)));
typedef float f32x4 __attribute__((ext_vector_type(4)));

__device__ __forceinline__ float fast_tanh(float x) {
  float e = __expf(2.0f * x);
  return 1.0f - 2.0f / (e + 1.0f);
}

__device__ __forceinline__ void gload_lds16(const void* g, void* l) {
  __builtin_amdgcn_global_load_lds(
      (const __attribute__((address_space(1))) unsigned int*)g,
      (__attribute__((address_space(3))) unsigned int*)l, 16, 0, 0);
}

// ---------------------------------------------------------------------------
// A [Mrows][512] fp32 -> A2 rows [m_off..m_off+Mrows) of [8 kt][Mtot][64] f16,
// XOR-swizzled per row (byte ^= (row&7)<<4) so linear global_load_lds staging
// + swizzled ds_read_b128 is bank-conflict-free (G21 both-sides rule).
// ---------------------------------------------------------------------------
template <bool TANH>
__global__ __launch_bounds__(256) void cvt_tile_kernel(
    const float* __restrict__ A, _Float16* __restrict__ A2,
    int Mtot, int m_off, int Mrows) {
  const int total = Mrows * 64;  // 16B chunks
  for (int i = blockIdx.x * 256 + threadIdx.x; i < total; i += gridDim.x * 256) {
    const int m = i >> 6, c = i & 63;
    const int kt = c >> 3, cc = c & 7;
    const float* src = A + (size_t)m * HDIM + c * 8;
    const float4 x = ((const float4*)src)[0];
    const float4 y = ((const float4*)src)[1];
    f16x8 h;
    if (TANH) {
      h[0] = (_Float16)fast_tanh(x.x); h[1] = (_Float16)fast_tanh(x.y);
      h[2] = (_Float16)fast_tanh(x.z); h[3] = (_Float16)fast_tanh(x.w);
      h[4] = (_Float16)fast_tanh(y.x); h[5] = (_Float16)fast_tanh(y.y);
      h[6] = (_Float16)fast_tanh(y.z); h[7] = (_Float16)fast_tanh(y.w);
    } else {
      h[0] = (_Float16)x.x; h[1] = (_Float16)x.y;
      h[2] = (_Float16)x.z; h[3] = (_Float16)x.w;
      h[4] = (_Float16)y.x; h[5] = (_Float16)y.y;
      h[6] = (_Float16)y.z; h[7] = (_Float16)y.w;
    }
    const int dr = m_off + m;
    char* dst = (char*)A2 + ((size_t)kt * Mtot + dr) * 128 + ((cc * 16) ^ ((dr & 7) << 4));
    *(f16x8*)dst = h;
  }
}

// W [512 k][512 n] fp32 -> W2 [8 kt][512 n][64 k] f16, XOR-swizzled by n.
__global__ __launch_bounds__(256) void cvt_w3_kernel(
    const float* __restrict__ Wt, const float* __restrict__ Wa,
    const float* __restrict__ Wd, _Float16* __restrict__ W2t,
    _Float16* __restrict__ W2a, _Float16* __restrict__ W2d) {
  const int i = blockIdx.x * 256 + threadIdx.x;  // 512*64
  if (i >= 512 * 64) return;
  const float* W = (blockIdx.y == 0) ? Wt : (blockIdx.y == 1) ? Wa : Wd;
  _Float16* W2 = (blockIdx.y == 0) ? W2t : (blockIdx.y == 1) ? W2a : W2d;
  const int n = i & 511, g = i >> 9;
  const int kt = g >> 3, cc = g & 7;
  f16x8 h;
#pragma unroll
  for (int j = 0; j < 8; ++j)
    h[j] = (_Float16)W[(size_t)(kt * 64 + cc * 8 + j) * HDIM + n];
  char* dst = (char*)W2 + ((size_t)kt * 512 + n) * 128 + ((cc * 16) ^ ((n & 7) << 4));
  *(f16x8*)dst = h;
}

// ---------------------------------------------------------------------------
// Fused logit GEMM, counted-vmcnt pipeline (T3-min + T4 + T5):
//   logits[m] += sum_n v[n] * tanh( (A@W)[m,n] + bias[n] )
// A2: [8][M][64] swizzled f16; W2: [8][512][64] swizzled f16.
// Block 128x128, BK=64, 512 thr = 8 waves (4M x 2N), wave tile 32x64.
// Per K-step: STAGE(t+1) -> s_waitcnt vmcnt(4) (tile t's loads done, t+1's
// stay in flight) -> s_barrier -> setprio(1) MFMA setprio(0) -> s_barrier.
// Never drains vmcnt to 0 mid-loop.
// ---------------------------------------------------------------------------
__global__ __launch_bounds__(512) void gemm_logits_pipe_kernel(
    const _Float16* __restrict__ A2, const _Float16* __restrict__ W2,
    const float* __restrict__ bias, const float* __restrict__ vvec,
    float* __restrict__ logits, int M) {
  __shared__ __align__(16) _Float16 As[2][128 * 64];  // 2 x 16 KB
  __shared__ __align__(16) _Float16 Bs[2][128 * 64];  // 2 x 16 KB

  const int tid = threadIdx.x;
  const int nwg = gridDim.x;
  const int qq = nwg >> 3;
  const int raw = blockIdx.x;
  const int swz = (raw & 7) * qq + (raw >> 3);  // XCD-bijective (nwg%8==0)
  const int nb = swz & 3;
  const int mb = swz >> 2;
  const size_t m0 = (size_t)mb * 128;
  const int n0 = nb * 128;

  const int lane = tid & 63, wid = tid >> 6;
  const int tx = lane & 15, qd = lane >> 4;
  const int wm = wid >> 1;   // 0..3 -> rows wm*32..+31
  const int wn = wid & 1;    // 0..1 -> cols wn*64..+63

  const char* gA = (const char*)A2 + m0 * 128;
  const char* gB = (const char*)W2 + (size_t)n0 * 128;
  const size_t sA = (size_t)M * 128;
  const size_t sB = (size_t)512 * 128;
  const int lo = tid * 16;         // 0..8191
  const int wlo = wid * 1024;      // wave-uniform LDS chunk base

  f32x4 acc[2][4];
#pragma unroll
  for (int i = 0; i < 2; ++i)
#pragma unroll
    for (int j = 0; j < 4; ++j) acc[i][j] = (f32x4){0.f, 0.f, 0.f, 0.f};

  auto STAGE = [&](int buf, int kt) {
    const char* a = gA + (size_t)kt * sA;
    const char* b = gB + (size_t)kt * sB;
#pragma unroll
    for (int p = 0; p < 2; ++p) {
      gload_lds16(a + lo + p * 8192, (char*)As[buf] + wlo + p * 8192);
      gload_lds16(b + lo + p * 8192, (char*)Bs[buf] + wlo + p * 8192);
    }
  };

  auto COMPUTE = [&](int buf) {
#pragma unroll
    for (int ks = 0; ks < 2; ++ks) {
      f16x8 aF[2], bF[4];
#pragma unroll
      for (int f = 0; f < 2; ++f) {
        const int row = wm * 32 + f * 16 + tx;
        int by = row * 128 + (ks * 32 + qd * 8) * 2;
        by ^= (row & 7) << 4;
        aF[f] = *(const f16x8*)((const char*)As[buf] + by);
      }
#pragma unroll
      for (int f = 0; f < 4; ++f) {
        const int n = wn * 64 + f * 16 + tx;
        int by = n * 128 + (ks * 32 + qd * 8) * 2;
        by ^= (n & 7) << 4;
        bF[f] = *(const f16x8*)((const char*)Bs[buf] + by);
      }
#pragma unroll
      for (int i = 0; i < 2; ++i)
#pragma unroll
        for (int j = 0; j < 4; ++j)
          acc[i][j] = __builtin_amdgcn_mfma_f32_16x16x32_f16(aF[i], bF[j], acc[i][j], 0, 0, 0);
    }
  };

  STAGE(0, 0);
#pragma unroll
  for (int t = 0; t < 8; ++t) {
    const int cur = t & 1;
    if (t < 7) {
      STAGE(cur ^ 1, t + 1);
      // tile t's 4 loads are the oldest; leave tile t+1's 4 in flight
      asm volatile("s_waitcnt vmcnt(4)" ::: "memory");
    } else {
      asm volatile("s_waitcnt vmcnt(0)" ::: "memory");
    }
    asm volatile("" ::: "memory");
    __builtin_amdgcn_s_barrier();
    asm volatile("" ::: "memory");
    __builtin_amdgcn_s_setprio(1);
    COMPUTE(cur);
    __builtin_amdgcn_s_setprio(0);
    asm volatile("" ::: "memory");
    __builtin_amdgcn_s_barrier();   // reads of buf[cur] done before t+2 overwrites
    asm volatile("" ::: "memory");
  }

  // epilogue: t = tanh(acc + bias[n]) * v[n], reduce over this block's 128 n's
  float vv[4], bb[4];
#pragma unroll
  for (int j = 0; j < 4; ++j) {
    const int n = n0 + wn * 64 + j * 16 + tx;
    vv[j] = vvec[n];
    bb[j] = bias[n];
  }
#pragma unroll
  for (int i = 0; i < 2; ++i) {
#pragma unroll
    for (int r = 0; r < 4; ++r) {
      float s = 0.0f;
#pragma unroll
      for (int j = 0; j < 4; ++j)
        s = fmaf(vv[j], fast_tanh(acc[i][j][r] + bb[j]), s);
      s += __shfl_xor(s, 1);
      s += __shfl_xor(s, 2);
      s += __shfl_xor(s, 4);
      s += __shfl_xor(s, 8);
      if (tx == 0)
        atomicAdd(&logits[m0 + wm * 32 + i * 16 + qd * 4 + r], s);
    }
  }
}

// ---------------------------------------------------------------------------
// small/streaming kernels
// ---------------------------------------------------------------------------

__global__ void zero_kernel(float* __restrict__ p, int n) {
  const int i = blockIdx.x * 256 + threadIdx.x;
  if (i < n) p[i] = 0.0f;
}

__global__ void seg_bounds_kernel(const int* __restrict__ seg, int N,
                                  int* __restrict__ seg_start) {
  const int b = threadIdx.x;
  if (b > BATCH) return;
  int lo = 0, hi = N;
  while (lo < hi) {
    const int mid = (lo + hi) >> 1;
    if (seg[mid] < b) lo = mid + 1; else hi = mid;
  }
  seg_start[b] = lo;
}

// grid (128, 4): y=0 token (S=512), y=1 desc-anchor, y=2 desc-neg, y=3 node-seg
__global__ __launch_bounds__(256) void softmax_all_kernel(
    float* __restrict__ ltok, float* __restrict__ ldesc,
    float* __restrict__ lnode, const int* __restrict__ tlen,
    const int* __restrict__ dalen, const int* __restrict__ dnlen,
    const int* __restrict__ seg_start) {
  __shared__ float smax[4], ssum[4];
  const int b = blockIdx.x, mode = blockIdx.y, tid = threadIdx.x;
  float* l;
  int s0, s1, fill_end;
  if (mode == 0)      { l = ltok + (size_t)b * 512;          s0 = 0; s1 = tlen[b];  fill_end = 512; }
  else if (mode == 1) { l = ldesc + (size_t)b * 128;         s0 = 0; s1 = dalen[b]; fill_end = 128; }
  else if (mode == 2) { l = ldesc + 16384 + (size_t)b * 128; s0 = 0; s1 = dnlen[b]; fill_end = 128; }
  else                { l = lnode; s0 = seg_start[b]; s1 = seg_start[b + 1]; fill_end = -1; }

  float mymax = -1e30f;
  for (int s = s0 + tid; s < s1; s += 256) mymax = fmaxf(mymax, l[s]);
#pragma unroll
  for (int off = 32; off; off >>= 1) mymax = fmaxf(mymax, __shfl_xor(mymax, off));
  if ((tid & 63) == 0) smax[tid >> 6] = mymax;
  __syncthreads();
  const float bmax = fmaxf(fmaxf(smax[0], smax[1]), fmaxf(smax[2], smax[3]));
  float mysum = 0.0f;
  for (int s = s0 + tid; s < s1; s += 256) mysum += __expf(l[s] - bmax);
#pragma unroll
  for (int off = 32; off; off >>= 1) mysum += __shfl_xor(mysum, off);
  if ((tid & 63) == 0) ssum[tid >> 6] = mysum;
  __syncthreads();
  const float inv = 1.0f / (ssum[0] + ssum[1] + ssum[2] + ssum[3]);
  for (int s = s0 + tid; s < s1; s += 256) l[s] = __expf(l[s] - bmax) * inv;
  if (fill_end > 0)
    for (int s = s1 + tid; s < fill_end; s += 256) l[s] = 0.0f;
}

// grid (128, 12): c<8 token chunks, c in {8,9} desc-anchor, {10,11} desc-neg
__global__ __launch_bounds__(256) void pool_masked_all_kernel(
    const _Float16* __restrict__ A2tok, const _Float16* __restrict__ A2desc,
    const float* __restrict__ ltok, const float* __restrict__ ldesc,
    float* __restrict__ tok_pool, float* __restrict__ da_pool,
    float* __restrict__ dn_pool) {
  const int b = blockIdx.x, c = blockIdx.y, tid = threadIdx.x;
  const _Float16* A2;
  const float* w;
  float* out;
  int Mtot, rbase, s0;
  if (c < 8)       { A2 = A2tok;  Mtot = 65536; rbase = b * 512;         w = ltok;  out = tok_pool; s0 = c * 64; }
  else if (c < 10) { A2 = A2desc; Mtot = 32768; rbase = b * 128;         w = ldesc; out = da_pool;  s0 = (c - 8) * 64; }
  else             { A2 = A2desc; Mtot = 32768; rbase = 16384 + b * 128; w = ldesc; out = dn_pool;  s0 = (c - 10) * 64; }
  const int h = tid * 2;
  const int kt = h >> 6, col = h & 63;
  const char* base = (const char*)A2 + (size_t)kt * Mtot * 128;
  float ax = 0.0f, ay = 0.0f;
  for (int s = s0; s < s0 + 64; ++s) {
    const int row = rbase + s;
    const float wsc = w[row];
    if (wsc != 0.0f) {
      const unsigned u = *(const unsigned*)(base + (size_t)row * 128 + ((col * 2) ^ ((row & 7) << 4)));
      const _Float16* hp = (const _Float16*)&u;
      ax = fmaf(wsc, (float)hp[0], ax);
      ay = fmaf(wsc, (float)hp[1], ay);
    }
  }
  atomicAdd(&out[b * HDIM + h], ax);
  atomicAdd(&out[b * HDIM + h + 1], ay);
}

// ast_pool[b,h] += sum_{n in seg b} w[n] * A2node[n,h] (tanh pre-applied)
__global__ __launch_bounds__(256) void pool_tiled_seg_kernel(
    const _Float16* __restrict__ A2, const float* __restrict__ w,
    const int* __restrict__ seg_start, float* __restrict__ pool, int Mtot) {
  const int b = blockIdx.x, c = blockIdx.y, tid = threadIdx.x;
  const int h = tid * 2;
  const int kt = h >> 6, col = h & 63;
  const char* base = (const char*)A2 + (size_t)kt * Mtot * 128;
  const int s0 = seg_start[b], s1 = seg_start[b + 1];
  const int nseg = s1 - s0;
  const int chunk = (nseg + (int)gridDim.y - 1) / (int)gridDim.y;
  const int a0 = s0 + c * chunk;
  const int a1 = min(s1, a0 + chunk);
  float ax = 0.0f, ay = 0.0f;
  for (int s = a0; s < a1; ++s) {
    const float wsc = w[s];
    const unsigned u = *(const unsigned*)(base + (size_t)s * 128 + ((col * 2) ^ ((s & 7) << 4)));
    const _Float16* hp = (const _Float16*)&u;
    ax = fmaf(wsc, (float)hp[0], ax);
    ay = fmaf(wsc, (float)hp[1], ay);
  }
  atomicAdd(&pool[b * HDIM + h], ax);
  atomicAdd(&pool[b * HDIM + h + 1], ay);
}

// code-pre GEMM: parts[kb][b][n-chunk] = cat[b][k-chunk] @ Wf[k-chunk][n-chunk]
__global__ __launch_bounds__(256) void code_gemm_kernel(
    const float* __restrict__ tok_pool, const float* __restrict__ ast_pool,
    const float* __restrict__ Wf, float* __restrict__ parts) {
  __shared__ float catS[128][65];
  __shared__ float4 wfS[64][32];
  const int nb = blockIdx.x, kb = blockIdx.y, tid = threadIdx.x;
  const int k0 = kb * 64;
  const float* src = (k0 < 512) ? (tok_pool + k0) : (ast_pool + (k0 - 512));
  for (int i = tid; i < 128 * 16; i += 256) {
    const int r = i >> 4, c4 = i & 15;
    const float4 v = *(const float4*)(src + (size_t)r * HDIM + c4 * 4);
    catS[r][c4 * 4 + 0] = fast_tanh(v.x);
    catS[r][c4 * 4 + 1] = fast_tanh(v.y);
    catS[r][c4 * 4 + 2] = fast_tanh(v.z);
    catS[r][c4 * 4 + 3] = fast_tanh(v.w);
  }
  for (int i = tid; i < 64 * 32; i += 256) {
    const int r = i >> 5, c = i & 31;
    wfS[r][c] = *(const float4*)(Wf + (size_t)(k0 + r) * HDIM + nb * 128 + c * 4);
  }
  __syncthreads();
  const int tb = tid >> 4, tn = tid & 15;
  const int b0 = tb * 8, n0l = tn * 8;
  float acc[8][8];
#pragma unroll
  for (int i = 0; i < 8; ++i)
#pragma unroll
    for (int j = 0; j < 8; ++j) acc[i][j] = 0.0f;
  for (int k = 0; k < 64; ++k) {
    float a[8];
#pragma unroll
    for (int i = 0; i < 8; ++i) a[i] = catS[b0 + i][k];
    const float4 w0 = wfS[k][tn * 2], w1 = wfS[k][tn * 2 + 1];
    const float wv[8] = {w0.x, w0.y, w0.z, w0.w, w1.x, w1.y, w1.z, w1.w};
#pragma unroll
    for (int i = 0; i < 8; ++i)
#pragma unroll
      for (int j = 0; j < 8; ++j) acc[i][j] = fmaf(a[i], wv[j], acc[i][j]);
  }
  float* dst = parts + ((size_t)kb * 128) * HDIM + nb * 128;
#pragma unroll
  for (int i = 0; i < 8; ++i) {
    const float4 o0 = {acc[i][0], acc[i][1], acc[i][2], acc[i][3]};
    const float4 o1 = {acc[i][4], acc[i][5], acc[i][6], acc[i][7]};
    *(float4*)(dst + (size_t)(b0 + i) * HDIM + n0l) = o0;
    *(float4*)(dst + (size_t)(b0 + i) * HDIM + n0l + 4) = o1;
  }
}

// per-sample hinge terms; folds code = tanh(sum_kb parts + bf). grid 128.
__global__ __launch_bounds__(256) void sims_kernel(
    const float* __restrict__ parts, const float* __restrict__ bfv,
    const float* __restrict__ da_pool, const float* __restrict__ dn_pool,
    float* __restrict__ terms) {
  __shared__ float sr[4][5];
  const int b = blockIdx.x, tid = threadIdx.x;
  float c2 = 0, a2 = 0, n2 = 0, ca = 0, cn = 0;
  for (int i = tid; i < HDIM; i += 256) {
    float pre = bfv[i];
#pragma unroll
    for (int kb = 0; kb < 16; ++kb)
      pre += parts[((size_t)kb * 128 + b) * HDIM + i];
    const float cf = fast_tanh(pre);
    const float av = fast_tanh(fast_tanh(da_pool[(size_t)b * HDIM + i]));
    const float nv = fast_tanh(fast_tanh(dn_pool[(size_t)b * HDIM + i]));
    c2 = fmaf(cf, cf, c2); a2 = fmaf(av, av, a2); n2 = fmaf(nv, nv, n2);
    ca = fmaf(cf, av, ca); cn = fmaf(cf, nv, cn);
  }
#pragma unroll
  for (int off = 32; off; off >>= 1) {
    c2 += __shfl_xor(c2, off); a2 += __shfl_xor(a2, off); n2 += __shfl_xor(n2, off);
    ca += __shfl_xor(ca, off); cn += __shfl_xor(cn, off);
  }
  const int wv = tid >> 6;
  if ((tid & 63) == 0) {
    sr[wv][0] = c2; sr[wv][1] = a2; sr[wv][2] = n2; sr[wv][3] = ca; sr[wv][4] = cn;
  }
  __syncthreads();
  if (tid == 0) {
    c2 = sr[0][0] + sr[1][0] + sr[2][0] + sr[3][0];
    a2 = sr[0][1] + sr[1][1] + sr[2][1] + sr[3][1];
    n2 = sr[0][2] + sr[1][2] + sr[2][2] + sr[3][2];
    ca = sr[0][3] + sr[1][3] + sr[2][3] + sr[3][3];
    cn = sr[0][4] + sr[1][4] + sr[2][4] + sr[3][4];
    const float nc = fmaxf(sqrtf(c2), 1e-8f);
    const float na = fmaxf(sqrtf(a2), 1e-8f);
    const float nn = fmaxf(sqrtf(n2), 1e-8f);
    terms[b] = fmaxf(0.05f - ca / (nc * na) + cn / (nc * nn), 1e-6f);
  }
}

__global__ void loss_kernel(const float* __restrict__ terms, float* __restrict__ out) {
  const int tid = threadIdx.x;  // 128
  float v = terms[tid];
#pragma unroll
  for (int off = 32; off; off >>= 1) v += __shfl_xor(v, off);
  __shared__ float sr[2];
  if ((tid & 63) == 0) sr[tid >> 6] = v;
  __syncthreads();
  if (tid == 0) out[0] = (sr[0] + sr[1]) * (1.0f / (float)BATCH);
}

// ===========================================================================

extern "C" void kernel_launch(void* const* d_in, const int* in_sizes, int n_in,
                              void* d_out, int out_size, void* d_ws, size_t ws_size,
                              hipStream_t stream) {
  (void)in_sizes; (void)n_in; (void)out_size; (void)ws_size;
  const float* token_feat = (const float*)d_in[0];
  const int*   token_len  = (const int*)d_in[1];
  const float* node_h     = (const float*)d_in[2];
  const int*   seg_ids    = (const int*)d_in[3];
  const float* da_feat    = (const float*)d_in[4];
  const int*   da_len     = (const int*)d_in[5];
  const float* dn_feat    = (const float*)d_in[6];
  const int*   dn_len     = (const int*)d_in[7];
  const float* Wt = (const float*)d_in[8];
  const float* bt = (const float*)d_in[9];
  const float* vt = (const float*)d_in[10];
  const float* Wa = (const float*)d_in[12];
  const float* ba = (const float*)d_in[13];
  const float* va = (const float*)d_in[14];
  const float* Wd = (const float*)d_in[16];
  const float* bd = (const float*)d_in[17];
  const float* vd = (const float*)d_in[18];
  const float* Wf  = (const float*)d_in[20];
  const float* bfv = (const float*)d_in[21];

  const int MTOK = 65536;   // 128*512
  const int MDESC2 = 32768; // 2*128*128 (anchor ++ neg)
  const int NNODES = 65536;

  float* ws = (float*)d_ws;
  float* logits_tok  = ws;                       // 65536
  float* logits_node = logits_tok + MTOK;        // 65536
  float* logits_desc = logits_node + NNODES;     // 32768 (da ++ dn)
  float* tok_pool    = logits_desc + MDESC2;     // 65536
  float* ast_pool    = tok_pool + 128 * HDIM;
  float* da_pool     = ast_pool + 128 * HDIM;
  float* dn_pool     = da_pool + 128 * HDIM;
  float* terms       = dn_pool + 128 * HDIM;     // 128
  int*   seg_start   = (int*)(terms + 128);      // 256 slot
  float* parts       = (float*)(seg_start + 256);  // 16*128*512
  _Float16* W2t = (_Float16*)(parts + 16 * 128 * HDIM);
  _Float16* W2a = W2t + HDIM * HDIM;
  _Float16* W2d = W2a + HDIM * HDIM;
  _Float16* A2tok  = W2d + HDIM * HDIM;              // 8*65536*64 f16
  _Float16* A2node = A2tok + (size_t)8 * MTOK * 64;
  _Float16* A2desc = A2node + (size_t)8 * NNODES * 64;  // 8*32768*64 f16

  // zero atomically-accumulated buffers: logits + 4 pools
  const int ZTOT = MTOK + NNODES + MDESC2 + 4 * 128 * HDIM;
  zero_kernel<<<dim3((ZTOT + 255) / 256), 256, 0, stream>>>(ws, ZTOT);
  seg_bounds_kernel<<<1, 256, 0, stream>>>(seg_ids, NNODES, seg_start);

  // convert weights + activations to tiled swizzled f16
  cvt_w3_kernel<<<dim3(128, 3), 256, 0, stream>>>(Wt, Wa, Wd, W2t, W2a, W2d);
  cvt_tile_kernel<false><<<2048, 256, 0, stream>>>(token_feat, A2tok, MTOK, 0, MTOK);
  cvt_tile_kernel<true ><<<2048, 256, 0, stream>>>(node_h, A2node, NNODES, 0, NNODES);
  cvt_tile_kernel<false><<<1024, 256, 0, stream>>>(da_feat, A2desc, MDESC2, 0, 16384);
  cvt_tile_kernel<false><<<1024, 256, 0, stream>>>(dn_feat, A2desc, MDESC2, 16384, 16384);

  // fused logit GEMMs (the +c constants are softmax-invariant, skipped)
  gemm_logits_pipe_kernel<<<MTOK / 128 * 4, 512, 0, stream>>>(A2tok, W2t, bt, vt, logits_tok, MTOK);
  gemm_logits_pipe_kernel<<<NNODES / 128 * 4, 512, 0, stream>>>(A2node, W2a, ba, va, logits_node, NNODES);
  gemm_logits_pipe_kernel<<<MDESC2 / 128 * 4, 512, 0, stream>>>(A2desc, W2d, bd, vd, logits_desc, MDESC2);

  softmax_all_kernel<<<dim3(BATCH, 4), 256, 0, stream>>>(
      logits_tok, logits_desc, logits_node, token_len, da_len, dn_len, seg_start);

  pool_masked_all_kernel<<<dim3(BATCH, 12), 256, 0, stream>>>(
      A2tok, A2desc, logits_tok, logits_desc, tok_pool, da_pool, dn_pool);
  pool_tiled_seg_kernel<<<dim3(BATCH, 4), 256, 0, stream>>>(
      A2node, logits_node, seg_start, ast_pool, NNODES);

  code_gemm_kernel<<<dim3(4, 16), 256, 0, stream>>>(tok_pool, ast_pool, Wf, parts);
  sims_kernel<<<BATCH, 256, 0, stream>>>(parts, bfv, da_pool, dn_pool, terms);
  loss_kernel<<<1, 128, 0, stream>>>(terms, (float*)d_out);
}

// Round 6
// 352.936 us; speedup vs baseline: 4.1852x; 1.0607x over previous
//
#include <hip/hip_runtime.h>
#include <math.h>

#define HDIM 512
#define BATCH 128

typedef _Float16 f16x8 __attribute__((ext_vector_type(8)));
typedef float f32x4 __attribute__((ext_vector_type(4)));

__device__ __forceinline__ float fast_tanh(float x) {
  float e = __expf(2.0f * x);
  return 1.0f - 2.0f / (e + 1.0f);
}

__device__ __forceinline__ void gload_lds16(const void* g, void* l) {
  __builtin_amdgcn_global_load_lds(
      (const __attribute__((address_space(1))) unsigned int*)g,
      (__attribute__((address_space(3))) unsigned int*)l, 16, 0, 0);
}

// ---------------------------------------------------------------------------
// A [Mrows][512] fp32 -> A2 rows [m_off..m_off+Mrows) of [8 kt][Mtot][64] f16,
// XOR-swizzled per row (byte ^= (row&7)<<4) so linear global_load_lds staging
// + swizzled ds_read_b128 is bank-conflict-free (G21 both-sides rule).
// ---------------------------------------------------------------------------
template <bool TANH>
__global__ __launch_bounds__(256) void cvt_tile_kernel(
    const float* __restrict__ A, _Float16* __restrict__ A2,
    int Mtot, int m_off, int Mrows) {
  const int total = Mrows * 64;  // 16B chunks
  for (int i = blockIdx.x * 256 + threadIdx.x; i < total; i += gridDim.x * 256) {
    const int m = i >> 6, c = i & 63;
    const int kt = c >> 3, cc = c & 7;
    const float* src = A + (size_t)m * HDIM + c * 8;
    const float4 x = ((const float4*)src)[0];
    const float4 y = ((const float4*)src)[1];
    f16x8 h;
    if (TANH) {
      h[0] = (_Float16)fast_tanh(x.x); h[1] = (_Float16)fast_tanh(x.y);
      h[2] = (_Float16)fast_tanh(x.z); h[3] = (_Float16)fast_tanh(x.w);
      h[4] = (_Float16)fast_tanh(y.x); h[5] = (_Float16)fast_tanh(y.y);
      h[6] = (_Float16)fast_tanh(y.z); h[7] = (_Float16)fast_tanh(y.w);
    } else {
      h[0] = (_Float16)x.x; h[1] = (_Float16)x.y;
      h[2] = (_Float16)x.z; h[3] = (_Float16)x.w;
      h[4] = (_Float16)y.x; h[5] = (_Float16)y.y;
      h[6] = (_Float16)y.z; h[7] = (_Float16)y.w;
    }
    const int dr = m_off + m;
    char* dst = (char*)A2 + ((size_t)kt * Mtot + dr) * 128 + ((cc * 16) ^ ((dr & 7) << 4));
    *(f16x8*)dst = h;
  }
}

// W [512 k][512 n] fp32 -> W2 [8 kt][512 n][64 k] f16, XOR-swizzled by n.
__global__ __launch_bounds__(256) void cvt_w3_kernel(
    const float* __restrict__ Wt, const float* __restrict__ Wa,
    const float* __restrict__ Wd, _Float16* __restrict__ W2t,
    _Float16* __restrict__ W2a, _Float16* __restrict__ W2d) {
  const int i = blockIdx.x * 256 + threadIdx.x;  // 512*64
  if (i >= 512 * 64) return;
  const float* W = (blockIdx.y == 0) ? Wt : (blockIdx.y == 1) ? Wa : Wd;
  _Float16* W2 = (blockIdx.y == 0) ? W2t : (blockIdx.y == 1) ? W2a : W2d;
  const int n = i & 511, g = i >> 9;
  const int kt = g >> 3, cc = g & 7;
  f16x8 h;
#pragma unroll
  for (int j = 0; j < 8; ++j)
    h[j] = (_Float16)W[(size_t)(kt * 64 + cc * 8 + j) * HDIM + n];
  char* dst = (char*)W2 + ((size_t)kt * 512 + n) * 128 + ((cc * 16) ^ ((n & 7) << 4));
  *(f16x8*)dst = h;
}

// ---------------------------------------------------------------------------
// Fused logit GEMM, 256x256 tile, 2-phase/K-tile interleaved pipeline:
//   logits[m] += sum_n v[n] * tanh( (A@W)[m,n] + bias[n] )
// A2: [8][M][64] swizzled f16; W2: [8][512][64] swizzled f16.
// 512 thr = 8 waves (2M x 4N), wave tile 128x64, acc 8x4, BK=64.
// LDS 128 KB (2 dbuf x (32KB A + 32KB B)). Per K-tile iteration:
//   ph0: issue A(t+1) -> vmcnt(4) [tile t's 8 drained, 4 in flight]
//        -> barrier -> 12 ds_read + 32 MFMA (setprio)
//   mid barrier (lockstep)
//   ph1: issue B(t+1) -> 12 ds_read + 32 MFMA (setprio) -> barrier
// Buffer overwrite hazards: stage(t+1) writes buf[cur^1], last read in
// iter t-1, protected by iter t-1's final barrier. Never vmcnt(0) mid-loop.
// ---------------------------------------------------------------------------
__global__ __launch_bounds__(512, 2) void gemm_logits_p2_kernel(
    const _Float16* __restrict__ A2, const _Float16* __restrict__ W2,
    const float* __restrict__ bias, const float* __restrict__ vvec,
    float* __restrict__ logits, int M) {
  __shared__ __align__(16) _Float16 As[2][256 * 64];  // 2 x 32 KB
  __shared__ __align__(16) _Float16 Bs[2][256 * 64];  // 2 x 32 KB

  const int tid = threadIdx.x;
  const int nwg = gridDim.x;
  const int qq = nwg >> 3;
  const int raw = blockIdx.x;
  const int swz = (raw & 7) * qq + (raw >> 3);  // XCD-bijective (nwg%8==0)
  const int nb = swz & 1;
  const int mb = swz >> 1;
  const size_t m0 = (size_t)mb * 256;
  const int n0 = nb * 256;

  const int lane = tid & 63, wid = tid >> 6;
  const int tx = lane & 15, qd = lane >> 4;
  const int wm = wid >> 2;   // 0..1 -> rows wm*128..+127
  const int wn = wid & 3;    // 0..3 -> cols wn*64..+63

  const char* gA = (const char*)A2 + m0 * 128;
  const char* gB = (const char*)W2 + (size_t)n0 * 128;
  const size_t sA = (size_t)M * 128;
  const size_t sB = (size_t)512 * 128;
  const int lo = tid * 16;       // 0..8191 per-lane global offset
  const int wlo = wid * 1024;    // wave-uniform LDS chunk base

  f32x4 acc[8][4];
#pragma unroll
  for (int i = 0; i < 8; ++i)
#pragma unroll
    for (int j = 0; j < 4; ++j) acc[i][j] = (f32x4){0.f, 0.f, 0.f, 0.f};

  auto STAGE_A = [&](int buf, int kt) {
    const char* a = gA + (size_t)kt * sA;
#pragma unroll
    for (int p = 0; p < 4; ++p)
      gload_lds16(a + lo + p * 8192, (char*)As[buf] + wlo + p * 8192);
  };
  auto STAGE_B = [&](int buf, int kt) {
    const char* b = gB + (size_t)kt * sB;
#pragma unroll
    for (int p = 0; p < 4; ++p)
      gload_lds16(b + lo + p * 8192, (char*)Bs[buf] + wlo + p * 8192);
  };

  auto HALF = [&](int buf, int ks) {
    f16x8 aF[8], bF[4];
#pragma unroll
    for (int i = 0; i < 8; ++i) {
      const int row = wm * 128 + i * 16 + tx;
      int by = row * 128 + (ks * 32 + qd * 8) * 2;
      by ^= (row & 7) << 4;
      aF[i] = *(const f16x8*)((const char*)As[buf] + by);
    }
#pragma unroll
    for (int j = 0; j < 4; ++j) {
      const int n = wn * 64 + j * 16 + tx;
      int by = n * 128 + (ks * 32 + qd * 8) * 2;
      by ^= (n & 7) << 4;
      bF[j] = *(const f16x8*)((const char*)Bs[buf] + by);
    }
    __builtin_amdgcn_s_setprio(1);
#pragma unroll
    for (int i = 0; i < 8; ++i)
#pragma unroll
      for (int j = 0; j < 4; ++j)
        acc[i][j] = __builtin_amdgcn_mfma_f32_16x16x32_f16(aF[i], bF[j], acc[i][j], 0, 0, 0);
    __builtin_amdgcn_s_setprio(0);
  };

  STAGE_A(0, 0);
  STAGE_B(0, 0);
#pragma unroll
  for (int t = 0; t < 8; ++t) {
    const int cur = t & 1;
    // --- phase 0 ---
    if (t < 7) {
      STAGE_A(cur ^ 1, t + 1);  // outstanding: 8 (tile t) + 4 (A of t+1)
      asm volatile("s_waitcnt vmcnt(4)" ::: "memory");  // drain tile t's 8
    } else {
      asm volatile("s_waitcnt vmcnt(0)" ::: "memory");
    }
    __builtin_amdgcn_s_barrier();
    asm volatile("" ::: "memory");
    HALF(cur, 0);
    asm volatile("" ::: "memory");
    __builtin_amdgcn_s_barrier();  // lockstep between phases
    asm volatile("" ::: "memory");
    // --- phase 1 ---
    if (t < 7) STAGE_B(cur ^ 1, t + 1);  // outstanding back to 8
    HALF(cur, 1);
    asm volatile("" ::: "memory");
    __builtin_amdgcn_s_barrier();  // all reads of buf[cur] done
    asm volatile("" ::: "memory");
  }

  // epilogue: t = tanh(acc + bias[n]) * v[n], reduce over this block's 256 n's
  float vv[4], bb[4];
#pragma unroll
  for (int j = 0; j < 4; ++j) {
    const int n = n0 + wn * 64 + j * 16 + tx;
    vv[j] = vvec[n];
    bb[j] = bias[n];
  }
#pragma unroll
  for (int i = 0; i < 8; ++i) {
#pragma unroll
    for (int r = 0; r < 4; ++r) {
      float s = 0.0f;
#pragma unroll
      for (int j = 0; j < 4; ++j)
        s = fmaf(vv[j], fast_tanh(acc[i][j][r] + bb[j]), s);
      s += __shfl_xor(s, 1);
      s += __shfl_xor(s, 2);
      s += __shfl_xor(s, 4);
      s += __shfl_xor(s, 8);
      if (tx == 0)
        atomicAdd(&logits[m0 + wm * 128 + i * 16 + qd * 4 + r], s);
    }
  }
}

// ---------------------------------------------------------------------------
// small/streaming kernels
// ---------------------------------------------------------------------------

__global__ void zero_kernel(float* __restrict__ p, int n) {
  const int i = blockIdx.x * 256 + threadIdx.x;
  if (i < n) p[i] = 0.0f;
}

__global__ void seg_bounds_kernel(const int* __restrict__ seg, int N,
                                  int* __restrict__ seg_start) {
  const int b = threadIdx.x;
  if (b > BATCH) return;
  int lo = 0, hi = N;
  while (lo < hi) {
    const int mid = (lo + hi) >> 1;
    if (seg[mid] < b) lo = mid + 1; else hi = mid;
  }
  seg_start[b] = lo;
}

// grid (128, 4): y=0 token (S=512), y=1 desc-anchor, y=2 desc-neg, y=3 node-seg
__global__ __launch_bounds__(256) void softmax_all_kernel(
    float* __restrict__ ltok, float* __restrict__ ldesc,
    float* __restrict__ lnode, const int* __restrict__ tlen,
    const int* __restrict__ dalen, const int* __restrict__ dnlen,
    const int* __restrict__ seg_start) {
  __shared__ float smax[4], ssum[4];
  const int b = blockIdx.x, mode = blockIdx.y, tid = threadIdx.x;
  float* l;
  int s0, s1, fill_end;
  if (mode == 0)      { l = ltok + (size_t)b * 512;          s0 = 0; s1 = tlen[b];  fill_end = 512; }
  else if (mode == 1) { l = ldesc + (size_t)b * 128;         s0 = 0; s1 = dalen[b]; fill_end = 128; }
  else if (mode == 2) { l = ldesc + 16384 + (size_t)b * 128; s0 = 0; s1 = dnlen[b]; fill_end = 128; }
  else                { l = lnode; s0 = seg_start[b]; s1 = seg_start[b + 1]; fill_end = -1; }

  float mymax = -1e30f;
  for (int s = s0 + tid; s < s1; s += 256) mymax = fmaxf(mymax, l[s]);
#pragma unroll
  for (int off = 32; off; off >>= 1) mymax = fmaxf(mymax, __shfl_xor(mymax, off));
  if ((tid & 63) == 0) smax[tid >> 6] = mymax;
  __syncthreads();
  const float bmax = fmaxf(fmaxf(smax[0], smax[1]), fmaxf(smax[2], smax[3]));
  float mysum = 0.0f;
  for (int s = s0 + tid; s < s1; s += 256) mysum += __expf(l[s] - bmax);
#pragma unroll
  for (int off = 32; off; off >>= 1) mysum += __shfl_xor(mysum, off);
  if ((tid & 63) == 0) ssum[tid >> 6] = mysum;
  __syncthreads();
  const float inv = 1.0f / (ssum[0] + ssum[1] + ssum[2] + ssum[3]);
  for (int s = s0 + tid; s < s1; s += 256) l[s] = __expf(l[s] - bmax) * inv;
  if (fill_end > 0)
    for (int s = s1 + tid; s < fill_end; s += 256) l[s] = 0.0f;
}

// grid (128, 12): c<8 token chunks, c in {8,9} desc-anchor, {10,11} desc-neg
__global__ __launch_bounds__(256) void pool_masked_all_kernel(
    const _Float16* __restrict__ A2tok, const _Float16* __restrict__ A2desc,
    const float* __restrict__ ltok, const float* __restrict__ ldesc,
    float* __restrict__ tok_pool, float* __restrict__ da_pool,
    float* __restrict__ dn_pool) {
  const int b = blockIdx.x, c = blockIdx.y, tid = threadIdx.x;
  const _Float16* A2;
  const float* w;
  float* out;
  int Mtot, rbase, s0;
  if (c < 8)       { A2 = A2tok;  Mtot = 65536; rbase = b * 512;         w = ltok;  out = tok_pool; s0 = c * 64; }
  else if (c < 10) { A2 = A2desc; Mtot = 32768; rbase = b * 128;         w = ldesc; out = da_pool;  s0 = (c - 8) * 64; }
  else             { A2 = A2desc; Mtot = 32768; rbase = 16384 + b * 128; w = ldesc; out = dn_pool;  s0 = (c - 10) * 64; }
  const int h = tid * 2;
  const int kt = h >> 6, col = h & 63;
  const char* base = (const char*)A2 + (size_t)kt * Mtot * 128;
  float ax = 0.0f, ay = 0.0f;
  for (int s = s0; s < s0 + 64; ++s) {
    const int row = rbase + s;
    const float wsc = w[row];
    if (wsc != 0.0f) {
      const unsigned u = *(const unsigned*)(base + (size_t)row * 128 + ((col * 2) ^ ((row & 7) << 4)));
      const _Float16* hp = (const _Float16*)&u;
      ax = fmaf(wsc, (float)hp[0], ax);
      ay = fmaf(wsc, (float)hp[1], ay);
    }
  }
  atomicAdd(&out[b * HDIM + h], ax);
  atomicAdd(&out[b * HDIM + h + 1], ay);
}

// ast_pool[b,h] += sum_{n in seg b} w[n] * A2node[n,h] (tanh pre-applied)
__global__ __launch_bounds__(256) void pool_tiled_seg_kernel(
    const _Float16* __restrict__ A2, const float* __restrict__ w,
    const int* __restrict__ seg_start, float* __restrict__ pool, int Mtot) {
  const int b = blockIdx.x, c = blockIdx.y, tid = threadIdx.x;
  const int h = tid * 2;
  const int kt = h >> 6, col = h & 63;
  const char* base = (const char*)A2 + (size_t)kt * Mtot * 128;
  const int s0 = seg_start[b], s1 = seg_start[b + 1];
  const int nseg = s1 - s0;
  const int chunk = (nseg + (int)gridDim.y - 1) / (int)gridDim.y;
  const int a0 = s0 + c * chunk;
  const int a1 = min(s1, a0 + chunk);
  float ax = 0.0f, ay = 0.0f;
  for (int s = a0; s < a1; ++s) {
    const float wsc = w[s];
    const unsigned u = *(const unsigned*)(base + (size_t)s * 128 + ((col * 2) ^ ((s & 7) << 4)));
    const _Float16* hp = (const _Float16*)&u;
    ax = fmaf(wsc, (float)hp[0], ax);
    ay = fmaf(wsc, (float)hp[1], ay);
  }
  atomicAdd(&pool[b * HDIM + h], ax);
  atomicAdd(&pool[b * HDIM + h + 1], ay);
}

// code-pre GEMM: parts[kb][b][n-chunk] = cat[b][k-chunk] @ Wf[k-chunk][n-chunk]
__global__ __launch_bounds__(256) void code_gemm_kernel(
    const float* __restrict__ tok_pool, const float* __restrict__ ast_pool,
    const float* __restrict__ Wf, float* __restrict__ parts) {
  __shared__ float catS[128][65];
  __shared__ float4 wfS[64][32];
  const int nb = blockIdx.x, kb = blockIdx.y, tid = threadIdx.x;
  const int k0 = kb * 64;
  const float* src = (k0 < 512) ? (tok_pool + k0) : (ast_pool + (k0 - 512));
  for (int i = tid; i < 128 * 16; i += 256) {
    const int r = i >> 4, c4 = i & 15;
    const float4 v = *(const float4*)(src + (size_t)r * HDIM + c4 * 4);
    catS[r][c4 * 4 + 0] = fast_tanh(v.x);
    catS[r][c4 * 4 + 1] = fast_tanh(v.y);
    catS[r][c4 * 4 + 2] = fast_tanh(v.z);
    catS[r][c4 * 4 + 3] = fast_tanh(v.w);
  }
  for (int i = tid; i < 64 * 32; i += 256) {
    const int r = i >> 5, c = i & 31;
    wfS[r][c] = *(const float4*)(Wf + (size_t)(k0 + r) * HDIM + nb * 128 + c * 4);
  }
  __syncthreads();
  const int tb = tid >> 4, tn = tid & 15;
  const int b0 = tb * 8, n0l = tn * 8;
  float acc[8][8];
#pragma unroll
  for (int i = 0; i < 8; ++i)
#pragma unroll
    for (int j = 0; j < 8; ++j) acc[i][j] = 0.0f;
  for (int k = 0; k < 64; ++k) {
    float a[8];
#pragma unroll
    for (int i = 0; i < 8; ++i) a[i] = catS[b0 + i][k];
    const float4 w0 = wfS[k][tn * 2], w1 = wfS[k][tn * 2 + 1];
    const float wv[8] = {w0.x, w0.y, w0.z, w0.w, w1.x, w1.y, w1.z, w1.w};
#pragma unroll
    for (int i = 0; i < 8; ++i)
#pragma unroll
      for (int j = 0; j < 8; ++j) acc[i][j] = fmaf(a[i], wv[j], acc[i][j]);
  }
  float* dst = parts + ((size_t)kb * 128) * HDIM + nb * 128;
#pragma unroll
  for (int i = 0; i < 8; ++i) {
    const float4 o0 = {acc[i][0], acc[i][1], acc[i][2], acc[i][3]};
    const float4 o1 = {acc[i][4], acc[i][5], acc[i][6], acc[i][7]};
    *(float4*)(dst + (size_t)(b0 + i) * HDIM + n0l) = o0;
    *(float4*)(dst + (size_t)(b0 + i) * HDIM + n0l + 4) = o1;
  }
}

// per-sample hinge terms; folds code = tanh(sum_kb parts + bf). grid 128.
__global__ __launch_bounds__(256) void sims_kernel(
    const float* __restrict__ parts, const float* __restrict__ bfv,
    const float* __restrict__ da_pool, const float* __restrict__ dn_pool,
    float* __restrict__ terms) {
  __shared__ float sr[4][5];
  const int b = blockIdx.x, tid = threadIdx.x;
  float c2 = 0, a2 = 0, n2 = 0, ca = 0, cn = 0;
  for (int i = tid; i < HDIM; i += 256) {
    float pre = bfv[i];
#pragma unroll
    for (int kb = 0; kb < 16; ++kb)
      pre += parts[((size_t)kb * 128 + b) * HDIM + i];
    const float cf = fast_tanh(pre);
    const float av = fast_tanh(fast_tanh(da_pool[(size_t)b * HDIM + i]));
    const float nv = fast_tanh(fast_tanh(dn_pool[(size_t)b * HDIM + i]));
    c2 = fmaf(cf, cf, c2); a2 = fmaf(av, av, a2); n2 = fmaf(nv, nv, n2);
    ca = fmaf(cf, av, ca); cn = fmaf(cf, nv, cn);
  }
#pragma unroll
  for (int off = 32; off; off >>= 1) {
    c2 += __shfl_xor(c2, off); a2 += __shfl_xor(a2, off); n2 += __shfl_xor(n2, off);
    ca += __shfl_xor(ca, off); cn += __shfl_xor(cn, off);
  }
  const int wv = tid >> 6;
  if ((tid & 63) == 0) {
    sr[wv][0] = c2; sr[wv][1] = a2; sr[wv][2] = n2; sr[wv][3] = ca; sr[wv][4] = cn;
  }
  __syncthreads();
  if (tid == 0) {
    c2 = sr[0][0] + sr[1][0] + sr[2][0] + sr[3][0];
    a2 = sr[0][1] + sr[1][1] + sr[2][1] + sr[3][1];
    n2 = sr[0][2] + sr[1][2] + sr[2][2] + sr[3][2];
    ca = sr[0][3] + sr[1][3] + sr[2][3] + sr[3][3];
    cn = sr[0][4] + sr[1][4] + sr[2][4] + sr[3][4];
    const float nc = fmaxf(sqrtf(c2), 1e-8f);
    const float na = fmaxf(sqrtf(a2), 1e-8f);
    const float nn = fmaxf(sqrtf(n2), 1e-8f);
    terms[b] = fmaxf(0.05f - ca / (nc * na) + cn / (nc * nn), 1e-6f);
  }
}

__global__ void loss_kernel(const float* __restrict__ terms, float* __restrict__ out) {
  const int tid = threadIdx.x;  // 128
  float v = terms[tid];
#pragma unroll
  for (int off = 32; off; off >>= 1) v += __shfl_xor(v, off);
  __shared__ float sr[2];
  if ((tid & 63) == 0) sr[tid >> 6] = v;
  __syncthreads();
  if (tid == 0) out[0] = (sr[0] + sr[1]) * (1.0f / (float)BATCH);
}

// ===========================================================================

extern "C" void kernel_launch(void* const* d_in, const int* in_sizes, int n_in,
                              void* d_out, int out_size, void* d_ws, size_t ws_size,
                              hipStream_t stream) {
  (void)in_sizes; (void)n_in; (void)out_size; (void)ws_size;
  const float* token_feat = (const float*)d_in[0];
  const int*   token_len  = (const int*)d_in[1];
  const float* node_h     = (const float*)d_in[2];
  const int*   seg_ids    = (const int*)d_in[3];
  const float* da_feat    = (const float*)d_in[4];
  const int*   da_len     = (const int*)d_in[5];
  const float* dn_feat    = (const float*)d_in[6];
  const int*   dn_len     = (const int*)d_in[7];
  const float* Wt = (const float*)d_in[8];
  const float* bt = (const float*)d_in[9];
  const float* vt = (const float*)d_in[10];
  const float* Wa = (const float*)d_in[12];
  const float* ba = (const float*)d_in[13];
  const float* va = (const float*)d_in[14];
  const float* Wd = (const float*)d_in[16];
  const float* bd = (const float*)d_in[17];
  const float* vd = (const float*)d_in[18];
  const float* Wf  = (const float*)d_in[20];
  const float* bfv = (const float*)d_in[21];

  const int MTOK = 65536;   // 128*512
  const int MDESC2 = 32768; // 2*128*128 (anchor ++ neg)
  const int NNODES = 65536;

  float* ws = (float*)d_ws;
  float* logits_tok  = ws;                       // 65536
  float* logits_node = logits_tok + MTOK;        // 65536
  float* logits_desc = logits_node + NNODES;     // 32768 (da ++ dn)
  float* tok_pool    = logits_desc + MDESC2;     // 65536
  float* ast_pool    = tok_pool + 128 * HDIM;
  float* da_pool     = ast_pool + 128 * HDIM;
  float* dn_pool     = da_pool + 128 * HDIM;
  float* terms       = dn_pool + 128 * HDIM;     // 128
  int*   seg_start   = (int*)(terms + 128);      // 256 slot
  float* parts       = (float*)(seg_start + 256);  // 16*128*512
  _Float16* W2t = (_Float16*)(parts + 16 * 128 * HDIM);
  _Float16* W2a = W2t + HDIM * HDIM;
  _Float16* W2d = W2a + HDIM * HDIM;
  _Float16* A2tok  = W2d + HDIM * HDIM;              // 8*65536*64 f16
  _Float16* A2node = A2tok + (size_t)8 * MTOK * 64;
  _Float16* A2desc = A2node + (size_t)8 * NNODES * 64;  // 8*32768*64 f16

  // zero atomically-accumulated buffers: logits + 4 pools
  const int ZTOT = MTOK + NNODES + MDESC2 + 4 * 128 * HDIM;
  zero_kernel<<<dim3((ZTOT + 255) / 256), 256, 0, stream>>>(ws, ZTOT);
  seg_bounds_kernel<<<1, 256, 0, stream>>>(seg_ids, NNODES, seg_start);

  // convert weights + activations to tiled swizzled f16
  cvt_w3_kernel<<<dim3(128, 3), 256, 0, stream>>>(Wt, Wa, Wd, W2t, W2a, W2d);
  cvt_tile_kernel<false><<<2048, 256, 0, stream>>>(token_feat, A2tok, MTOK, 0, MTOK);
  cvt_tile_kernel<true ><<<2048, 256, 0, stream>>>(node_h, A2node, NNODES, 0, NNODES);
  cvt_tile_kernel<false><<<1024, 256, 0, stream>>>(da_feat, A2desc, MDESC2, 0, 16384);
  cvt_tile_kernel<false><<<1024, 256, 0, stream>>>(dn_feat, A2desc, MDESC2, 16384, 16384);

  // fused logit GEMMs (the +c constants are softmax-invariant, skipped)
  gemm_logits_p2_kernel<<<MTOK / 256 * 2, 512, 0, stream>>>(A2tok, W2t, bt, vt, logits_tok, MTOK);
  gemm_logits_p2_kernel<<<NNODES / 256 * 2, 512, 0, stream>>>(A2node, W2a, ba, va, logits_node, NNODES);
  gemm_logits_p2_kernel<<<MDESC2 / 256 * 2, 512, 0, stream>>>(A2desc, W2d, bd, vd, logits_desc, MDESC2);

  softmax_all_kernel<<<dim3(BATCH, 4), 256, 0, stream>>>(
      logits_tok, logits_desc, logits_node, token_len, da_len, dn_len, seg_start);

  pool_masked_all_kernel<<<dim3(BATCH, 12), 256, 0, stream>>>(
      A2tok, A2desc, logits_tok, logits_desc, tok_pool, da_pool, dn_pool);
  pool_tiled_seg_kernel<<<dim3(BATCH, 4), 256, 0, stream>>>(
      A2node, logits_node, seg_start, ast_pool, NNODES);

  code_gemm_kernel<<<dim3(4, 16), 256, 0, stream>>>(tok_pool, ast_pool, Wf, parts);
  sims_kernel<<<BATCH, 256, 0, stream>>>(parts, bfv, da_pool, dn_pool, terms);
  loss_kernel<<<1, 128, 0, stream>>>(terms, (float*)d_out);
}